// Round 14
// baseline (1030.532 us; speedup 1.0000x reference)
//
#include <hip/hip_runtime.h>
#include <math.h>

#define TAN30f 0.57735026918962576f
#define SELU_SCALE 1.0507009873554805f
#define SELU_ALPHA 1.6732632423543772f

#define MAXC 65536   // max grid cells
#define MAXG 40
#define BBOXBLK 64

__device__ __forceinline__ float selu_f(float x) {
    return SELU_SCALE * (x > 0.0f ? x : SELU_ALPHA * expm1f(x));
}

struct GP {
    float ox, oy, oz, ihx, ihy, ihz, hmin2, pad;
    int Gx, Gy, Gz, maxG;
};

// ---------- dense matmul: Y[N,128] = concat(X[N,FIC], P[N,3]?) @ W ----------
template<int FIC, bool HAS_POS, bool BIAS_SELU, bool ROWSCALE>
__global__ __launch_bounds__(256) void k_matmul128(
    const float* __restrict__ X, const float* __restrict__ P,
    const float* __restrict__ W, const float* __restrict__ bias,
    const float* __restrict__ rs,
    float* __restrict__ Y, int N)
{
    constexpr int ICT = FIC + (HAS_POS ? 3 : 0);
    __shared__ float xs[16][ICT + 1];
    int row0 = blockIdx.x * 16;

    for (int idx = threadIdx.x; idx < 16 * FIC; idx += 256) {
        int r = idx / FIC, c = idx % FIC;
        int gr = row0 + r;
        xs[r][c] = (gr < N) ? X[gr * FIC + c] : 0.0f;
    }
    if (HAS_POS) {
        for (int idx = threadIdx.x; idx < 16 * 3; idx += 256) {
            int r = idx / 3, c = idx % 3;
            int gr = row0 + r;
            xs[r][FIC + c] = (gr < N) ? P[gr * 3 + c] : 0.0f;
        }
    }
    __syncthreads();

    int col = threadIdx.x & 127;
    int half = threadIdx.x >> 7;
    float acc[8];
#pragma unroll
    for (int r = 0; r < 8; ++r) acc[r] = 0.0f;

#pragma unroll 4
    for (int i = 0; i < ICT; ++i) {
        float wv = W[i * 128 + col];
#pragma unroll
        for (int r = 0; r < 8; ++r)
            acc[r] = fmaf(xs[half * 8 + r][i], wv, acc[r]);
    }

    float bv = BIAS_SELU ? bias[col] : 0.0f;
#pragma unroll
    for (int r = 0; r < 8; ++r) {
        int gr = row0 + half * 8 + r;
        if (gr < N) {
            float v = acc[r];
            if (BIAS_SELU) v = selu_f(v + bv);
            if (ROWSCALE) v *= rs[gr];
            Y[gr * 128 + col] = v;
        }
    }
}

// ---------- batched triple graph build (all levels at once) ----------
__global__ void k_hist3(const int* __restrict__ c0, int E0, int* __restrict__ n0,
                        const int* __restrict__ c1, int E1, int* __restrict__ n1,
                        const int* __restrict__ c2, int E2, int* __restrict__ n2) {
    int i = blockIdx.x * 256 + threadIdx.x;
    if (i < E0) atomicAdd(&n0[c0[i]], 1);
    else if (i < E0 + E1) atomicAdd(&n1[c1[i - E0]], 1);
    else if (i < E0 + E1 + E2) atomicAdd(&n2[c2[i - E0 - E1]], 1);
}

__global__ __launch_bounds__(256) void k_scan1t(
    const int* __restrict__ in0, int* __restrict__ out0, float* __restrict__ dva, int n0a,
    const int* __restrict__ in1, int* __restrict__ out1, float* __restrict__ dvb, int n1a,
    const int* __restrict__ in2, int* __restrict__ out2, float* __restrict__ dvc, int n2a,
    int* __restrict__ bsum, int nbmax)
{
    int y = blockIdx.y;
    const int* in = y == 0 ? in0 : (y == 1 ? in1 : in2);
    int* out = y == 0 ? out0 : (y == 1 ? out1 : out2);
    float* dv = y == 0 ? dva : (y == 1 ? dvb : dvc);
    int n = y == 0 ? n0a : (y == 1 ? n1a : n2a);
    __shared__ int s[256];
    int tid = threadIdx.x;
    int base = blockIdx.x * 1024 + tid * 4;
    int a[4];
#pragma unroll
    for (int k = 0; k < 4; ++k) a[k] = (base + k < n) ? in[base + k] : 0;
#pragma unroll
    for (int k = 0; k < 4; ++k)
        if (base + k < n) dv[base + k] = rsqrtf((float)a[k] + 1.0f);
    int t = a[0] + a[1] + a[2] + a[3];
    s[tid] = t;
    __syncthreads();
    for (int off = 1; off < 256; off <<= 1) {
        int x = (tid >= off) ? s[tid - off] : 0;
        __syncthreads();
        s[tid] += x;
        __syncthreads();
    }
    int run = s[tid] - t;
#pragma unroll
    for (int k = 0; k < 4; ++k) {
        if (base + k < n) out[base + k] = run;
        run += a[k];
    }
    if (tid == 255) bsum[y * nbmax + blockIdx.x] = s[255];
}

__global__ void k_scan2(int* __restrict__ bsum, int nb) {
    if (threadIdx.x == 0) {
        int* b = bsum + blockIdx.x * nb;
        int run = 0;
        for (int i = 0; i < nb; ++i) { int v = b[i]; b[i] = run; run += v; }
    }
}

__global__ void k_scan3t(int* __restrict__ rp0, int* __restrict__ cu0, int E0, int n0a,
                         int* __restrict__ rp1, int* __restrict__ cu1, int E1, int n1a,
                         int* __restrict__ rp2, int* __restrict__ cu2, int E2, int n2a,
                         const int* __restrict__ bsum, int nbmax) {
    int y = blockIdx.y;
    int* rp = y == 0 ? rp0 : (y == 1 ? rp1 : rp2);
    int* cu = y == 0 ? cu0 : (y == 1 ? cu1 : cu2);
    int E = y == 0 ? E0 : (y == 1 ? E1 : E2);
    int n = y == 0 ? n0a : (y == 1 ? n1a : n2a);
    const int* bs = bsum + y * nbmax;
    int i = blockIdx.x * 256 + threadIdx.x;
    if (i < n) {
        int v = rp[i] + bs[i >> 10];
        rp[i] = v;
        cu[i] = v;
    }
    if (i == 0) rp[n] = E;
}

__global__ void k_scatter3(const int* __restrict__ ei0, int E0, int* __restrict__ cu0, int* __restrict__ cs0,
                           const int* __restrict__ ei1, int E1, int* __restrict__ cu1, int* __restrict__ cs1,
                           const int* __restrict__ ei2, int E2, int* __restrict__ cu2, int* __restrict__ cs2) {
    int i = blockIdx.x * 256 + threadIdx.x;
    const int* ei; int E; int* cur; int* csr; int e;
    if (i < E0)               { ei = ei0; E = E0; cur = cu0; csr = cs0; e = i; }
    else if (i < E0 + E1)     { ei = ei1; E = E1; cur = cu1; csr = cs1; e = i - E0; }
    else if (i < E0 + E1 + E2){ ei = ei2; E = E2; cur = cu2; csr = cs2; e = i - E0 - E1; }
    else return;
    int r = ei[e], c = ei[E + e];
    int p = atomicAdd(&cur[c], 1);
    csr[p] = r;
}

// ---------- CSR gather aggregation, float4-vectorized (32 thr/node) ----------
__global__ __launch_bounds__(256) void k_gather128(
    const int* __restrict__ rowptr, const int* __restrict__ csr,
    const float4* __restrict__ xws4, const float* __restrict__ dv,
    const float4* __restrict__ bias4, float4* __restrict__ out4, int N)
{
    int t = blockIdx.x * 256 + threadIdx.x;
    int node = t >> 5, c4 = t & 31;
    if (node >= N) return;
    int s = rowptr[node], e = rowptr[node + 1];
    float4 acc = xws4[(size_t)node * 32 + c4];  // self loop (already *dinv[node])
    for (int i = s; i < e; ++i) {
        int src = csr[i];
        float4 v = xws4[(size_t)src * 32 + c4];
        acc.x += v.x; acc.y += v.y; acc.z += v.z; acc.w += v.w;
    }
    float d = dv[node];
    float4 b = bias4[c4];
    float4 o;
    o.x = selu_f(fmaf(acc.x, d, b.x));
    o.y = selu_f(fmaf(acc.y, d, b.y));
    o.z = selu_f(fmaf(acc.z, d, b.z));
    o.w = selu_f(fmaf(acc.w, d, b.w));
    out4[(size_t)node * 32 + c4] = o;
}

__global__ __launch_bounds__(256) void k_gather5(
    const int* __restrict__ rowptr, const int* __restrict__ csr,
    const float* __restrict__ xws, const float* __restrict__ dv,
    const float* __restrict__ bias, float* __restrict__ out, int N)
{
    int t = blockIdx.x * 256 + threadIdx.x;
    int node = t >> 3, ch = t & 7;
    if (node >= N || ch >= 5) return;
    int s = rowptr[node], e = rowptr[node + 1];
    float acc = xws[(size_t)node * 5 + ch];
    for (int i = s; i < e; ++i) {
        int src = csr[i];
        acc += xws[(size_t)src * 5 + ch];
    }
    out[(size_t)node * 5 + ch] = acc * dv[node] + bias[ch];
}

// ---------- onera transform (all 3 levels fused); emits {x,y,z,|p|^2} ----------
__global__ void k_transform3(const float* __restrict__ p0, float4* __restrict__ t0, int n0,
                             const float* __restrict__ p1, float4* __restrict__ t1, int n1,
                             const float* __restrict__ p2, float4* __restrict__ t2, int n2) {
    int i = blockIdx.x * 256 + threadIdx.x;
    const float* pos; float4* tp; int li;
    if (i < n0) { pos = p0; tp = t0; li = i; }
    else if (i < n0 + n1) { pos = p1; tp = t1; li = i - n0; }
    else if (i < n0 + n1 + n2) { pos = p2; tp = t2; li = i - n0 - n1; }
    else return;
    float x = pos[li * 3 + 0], y = pos[li * 3 + 1], z = pos[li * 3 + 2];
    float nx = x - TAN30f * y;
    float f = 1.0f + (1.0f / 0.56f - 1.0f) * (y / 1.1963f);
    float X = nx * f, Y = y * f, Z = z * f;
    tp[li] = make_float4(X, Y, Z, (X * X + Y * Y) + Z * Z);
}

// ---------- spatial grid kNN (both levels fused) ----------
__global__ __launch_bounds__(256) void k_bbox2(const float4* __restrict__ tpa, int na,
                                               const float4* __restrict__ tpb, int nb,
                                               float* __restrict__ bbp) {
    const float4* tp = blockIdx.y ? tpb : tpa;
    int n = blockIdx.y ? nb : na;
    __shared__ float red[6][256];
    float mn0 = 3.4e38f, mn1 = 3.4e38f, mn2 = 3.4e38f;
    float mx0 = -3.4e38f, mx1 = -3.4e38f, mx2 = -3.4e38f;
    for (int i = blockIdx.x * 256 + threadIdx.x; i < n; i += gridDim.x * 256) {
        float4 t = tp[i];
        mn0 = fminf(mn0, t.x); mx0 = fmaxf(mx0, t.x);
        mn1 = fminf(mn1, t.y); mx1 = fmaxf(mx1, t.y);
        mn2 = fminf(mn2, t.z); mx2 = fmaxf(mx2, t.z);
    }
    int tid = threadIdx.x;
    red[0][tid] = mn0; red[1][tid] = mn1; red[2][tid] = mn2;
    red[3][tid] = mx0; red[4][tid] = mx1; red[5][tid] = mx2;
    __syncthreads();
    for (int off = 128; off > 0; off >>= 1) {
        if (tid < off) {
#pragma unroll
            for (int k = 0; k < 3; ++k) {
                red[k][tid] = fminf(red[k][tid], red[k][tid + off]);
                red[3 + k][tid] = fmaxf(red[3 + k][tid], red[3 + k][tid + off]);
            }
        }
        __syncthreads();
    }
    if (tid == 0) {
        float* o = bbp + (blockIdx.y * BBOXBLK + blockIdx.x) * 6;
#pragma unroll
        for (int k = 0; k < 3; ++k) {
            o[k] = red[k][0];
            o[3 + k] = red[3 + k][0];
        }
    }
}

__global__ void k_gridparams2(const float* __restrict__ bbp, int na, int nb,
                              GP* __restrict__ gps) {
    if (threadIdx.x != 0) return;
    int set = blockIdx.x;
    const float* bp = bbp + set * BBOXBLK * 6;
    int n = set ? nb : na;
    GP* gp = gps + set;
    float mn[3] = {3.4e38f, 3.4e38f, 3.4e38f};
    float mx[3] = {-3.4e38f, -3.4e38f, -3.4e38f};
    for (int i = 0; i < BBOXBLK; ++i) {
#pragma unroll
        for (int k = 0; k < 3; ++k) {
            mn[k] = fminf(mn[k], bp[i * 6 + k]);
            mx[k] = fmaxf(mx[k], bp[i * 6 + 3 + k]);
        }
    }
    float e[3], o[3];
#pragma unroll
    for (int k = 0; k < 3; ++k) {
        float ext = fmaxf(mx[k] - mn[k], 1e-6f);
        float padv = ext * 1e-4f + 1e-6f;
        o[k] = mn[k] - padv;
        e[k] = ext + 2.0f * padv;
    }
    float T = (float)n * 0.2f;  // target ~5 pts/cell
    float s = cbrtf(T / (e[0] * e[1] * e[2]));
    int G[3];
#pragma unroll
    for (int k = 0; k < 3; ++k) {
        int g = (int)ceilf(e[k] * s);
        G[k] = g < 1 ? 1 : (g > MAXG ? MAXG : g);
    }
    float h[3];
#pragma unroll
    for (int k = 0; k < 3; ++k) h[k] = e[k] / (float)G[k];
    float hmin = fminf(h[0], fminf(h[1], h[2]));
    gp->ox = o[0]; gp->oy = o[1]; gp->oz = o[2];
    gp->ihx = (float)G[0] / e[0]; gp->ihy = (float)G[1] / e[1]; gp->ihz = (float)G[2] / e[2];
    gp->hmin2 = hmin * hmin;
    gp->Gx = G[0]; gp->Gy = G[1]; gp->Gz = G[2];
    gp->maxG = max(G[0], max(G[1], G[2]));
}

__device__ __forceinline__ int cell_of(float4 t, const GP* gp) {
    int cx = min(max((int)((t.x - gp->ox) * gp->ihx), 0), gp->Gx - 1);
    int cy = min(max((int)((t.y - gp->oy) * gp->ihy), 0), gp->Gy - 1);
    int cz = min(max((int)((t.z - gp->oz) * gp->ihz), 0), gp->Gz - 1);
    return (cz * gp->Gy + cy) * gp->Gx + cx;
}

// 4 segments: ref0 (tp0,gp0) | q1 (tp1,gp0) | ref1 (tp1,gp1) | q2 (tp2,gp1)
__global__ void k_cellid4(const float4* __restrict__ tp0, int N0,
                          const float4* __restrict__ tp1, int N1,
                          const float4* __restrict__ tp2, int N2,
                          int* __restrict__ gcell0, int* __restrict__ qcell1,
                          int* __restrict__ gcell1, int* __restrict__ qcell2,
                          int* __restrict__ cnt, const GP* __restrict__ gps) {
    int i = blockIdx.x * 256 + threadIdx.x;
    const float4* tp; const GP* gp; int* cellout; int* cn; int li;
    if (i < N0)                { tp = tp0; gp = gps;     cellout = gcell0; cn = cnt;            li = i; }
    else if (i < N0 + N1)      { tp = tp1; gp = gps;     cellout = qcell1; cn = cnt + MAXC;     li = i - N0; }
    else if (i < N0 + 2 * N1)  { tp = tp1; gp = gps + 1; cellout = gcell1; cn = cnt + 2 * MAXC; li = i - N0 - N1; }
    else if (i < N0 + 2 * N1 + N2) { tp = tp2; gp = gps + 1; cellout = qcell2; cn = cnt + 3 * MAXC; li = i - N0 - 2 * N1; }
    else return;
    int cid = cell_of(tp[li], gp);
    cellout[li] = cid;
    atomicAdd(&cn[cid], 1);
}

__global__ __launch_bounds__(256) void k_scan1c(const int* __restrict__ cnt,
                                                int* __restrict__ row,
                                                int* __restrict__ bsum, int nb) {
    const int* in = cnt + blockIdx.y * MAXC;
    int* out = row + blockIdx.y * (MAXC + 1);
    __shared__ int s[256];
    int tid = threadIdx.x;
    int base = blockIdx.x * 1024 + tid * 4;
    int a[4];
#pragma unroll
    for (int k = 0; k < 4; ++k) a[k] = (base + k < MAXC) ? in[base + k] : 0;
    int t = a[0] + a[1] + a[2] + a[3];
    s[tid] = t;
    __syncthreads();
    for (int off = 1; off < 256; off <<= 1) {
        int x = (tid >= off) ? s[tid - off] : 0;
        __syncthreads();
        s[tid] += x;
        __syncthreads();
    }
    int run = s[tid] - t;
#pragma unroll
    for (int k = 0; k < 4; ++k) {
        if (base + k < MAXC) out[base + k] = run;
        run += a[k];
    }
    if (tid == 255) bsum[blockIdx.y * nb + blockIdx.x] = s[255];
}

__global__ void k_scan3c(int* __restrict__ row, int* __restrict__ cur,
                         const int* __restrict__ bsum, int nb, int4 E4) {
    int y = blockIdx.y;
    int* rp = row + y * (MAXC + 1);
    int* cu = cur + y * MAXC;
    const int* bs = bsum + y * nb;
    int E = (y == 0) ? E4.x : (y == 1) ? E4.y : (y == 2) ? E4.z : E4.w;
    int i = blockIdx.x * 256 + threadIdx.x;
    if (i < MAXC) {
        int v = rp[i] + bs[i >> 10];
        rp[i] = v;
        cu[i] = v;
    }
    if (i == 0) rp[MAXC] = E;
}

__global__ void k_scatter4(const float4* __restrict__ tp0, int N0,
                           const float4* __restrict__ tp1, int N1,
                           const float4* __restrict__ tp2, int N2,
                           const int* __restrict__ gcell0, const int* __restrict__ qcell1,
                           const int* __restrict__ gcell1, const int* __restrict__ qcell2,
                           int* __restrict__ cur,
                           float4* __restrict__ gpts0, float4* __restrict__ gpts1,
                           int* __restrict__ qorder1, int* __restrict__ qorder2) {
    int i = blockIdx.x * 256 + threadIdx.x;
    if (i < N0) {
        int p = atomicAdd(&cur[gcell0[i]], 1);
        float4 t = tp0[i];
        t.w = __int_as_float(i);
        gpts0[p] = t;
    } else if (i < N0 + N1) {
        int j = i - N0;
        int p = atomicAdd(&cur[MAXC + qcell1[j]], 1);
        qorder1[p] = j;
    } else if (i < N0 + 2 * N1) {
        int j = i - N0 - N1;
        int p = atomicAdd(&cur[2 * MAXC + gcell1[j]], 1);
        float4 t = tp1[j];
        t.w = __int_as_float(j);
        gpts1[p] = t;
    } else if (i < N0 + 2 * N1 + N2) {
        int j = i - N0 - 2 * N1;
        int p = atomicAdd(&cur[3 * MAXC + qcell2[j]], 1);
        qorder2[p] = j;
    }
}

// Both levels' searches in one launch; point scan unrolled x8 for MLP.
__global__ __launch_bounds__(256) void k_knn_grid2(
    const float4* __restrict__ tpq1, int N1, const int* __restrict__ qorder1,
    const float4* __restrict__ gpts0, const int* __restrict__ crow0,
    int* __restrict__ oidx1, float* __restrict__ ow1,
    const float4* __restrict__ tpq2, int N2, const int* __restrict__ qorder2,
    const float4* __restrict__ gpts1, const int* __restrict__ crow1,
    int* __restrict__ oidx2, float* __restrict__ ow2,
    const GP* __restrict__ gps)
{
    int t = blockIdx.x * 256 + threadIdx.x;
    const float4* tpq; const int* qord; const float4* gpts; const int* crow;
    const GP* gp; int* oidx; float* ow; int slot; int Nq;
    if (t < N1) {
        tpq = tpq1; qord = qorder1; gpts = gpts0; crow = crow0;
        gp = gps; oidx = oidx1; ow = ow1; slot = t; Nq = N1;
    } else {
        tpq = tpq2; qord = qorder2; gpts = gpts1; crow = crow1;
        gp = gps + 1; oidx = oidx2; ow = ow2; slot = t - N1; Nq = N2;
    }
    bool active = slot < Nq;
    int qi = active ? qord[slot] : 0;

    float ox = gp->ox, oy = gp->oy, oz = gp->oz;
    float ihx = gp->ihx, ihy = gp->ihy, ihz = gp->ihz;
    float hmin2 = gp->hmin2;
    int Gx = gp->Gx, Gy = gp->Gy, Gz = gp->Gz, maxG = gp->maxG;

    float qx = 0, qy = 0, qz = 0, q2 = 0;
    if (active) { float4 tq = tpq[qi]; qx = tq.x; qy = tq.y; qz = tq.z; q2 = tq.w; }
    int cx = min(max((int)((qx - ox) * ihx), 0), Gx - 1);
    int cy = min(max((int)((qy - oy) * ihy), 0), Gy - 1);
    int cz = min(max((int)((qz - oz) * ihz), 0), Gz - 1);

    float d0 = 3.4e38f, d1 = 3.4e38f, d2 = 3.4e38f;
    int j0 = 0x7FFFFFFF, j1 = 0x7FFFFFFF, j2 = 0x7FFFFFFF;

    auto insert = [&](float d, int id) {
        // lexicographic (d, id) — matches top_k tie order
        if (d < d2 || (d == d2 && id < j2)) {
            if (d < d1 || (d == d1 && id < j1)) {
                d2 = d1; j2 = j1;
                if (d < d0 || (d == d0 && id < j0)) {
                    d1 = d0; j1 = j0; d0 = d; j0 = id;
                } else { d1 = d; j1 = id; }
            } else { d2 = d; j2 = id; }
        }
    };
    auto proc = [&](float4 p) {
        int id = __float_as_int(p.w);
        float px2 = fmaf(p.z, p.z, fmaf(p.y, p.y, p.x * p.x));
        float dot = fmaf(p.z, qz, fmaf(p.y, qy, p.x * qx));
        float d = (q2 - 2.0f * dot) + px2;
        insert(d, id);
    };
    auto scan_range = [&](int s, int e) {
        int i = s;
        for (; i + 7 < e; i += 8) {
            float4 pa = gpts[i],     pb = gpts[i + 1], pc = gpts[i + 2], pd = gpts[i + 3];
            float4 pe = gpts[i + 4], pf = gpts[i + 5], pg = gpts[i + 6], ph = gpts[i + 7];
            proc(pa); proc(pb); proc(pc); proc(pd);
            proc(pe); proc(pf); proc(pg); proc(ph);
        }
        for (; i + 3 < e; i += 4) {
            float4 pa = gpts[i], pb = gpts[i + 1], pc = gpts[i + 2], pd = gpts[i + 3];
            proc(pa); proc(pb); proc(pc); proc(pd);
        }
        for (; i < e; ++i) { float4 p = gpts[i]; proc(p); }
    };
    auto scan_cells = [&](int zz, int yy, int xlo, int xhi) {
        int base = (zz * Gy + yy) * Gx;
        scan_range(crow[base + xlo], crow[base + xhi + 1]);
    };

    {
        int xlo = max(cx - 1, 0), xhi = min(cx + 1, Gx - 1);
        int rs[9], re[9];
#pragma unroll
        for (int k = 0; k < 9; ++k) {
            int zz = cz + k / 3 - 1, yy = cy + k % 3 - 1;
            bool ok = active && zz >= 0 && zz < Gz && yy >= 0 && yy < Gy;
            int base = ok ? (zz * Gy + yy) * Gx : 0;
            int a = crow[base + (ok ? xlo : 0)];
            int b = crow[base + (ok ? xhi + 1 : 0)];
            rs[k] = ok ? a : 0;
            re[k] = ok ? b : 0;
        }
#pragma unroll
        for (int k = 0; k < 9; ++k) scan_range(rs[k], re[k]);
    }
    bool done = !active || (d2 < hmin2);   // guarantee radius 1*hmin after r=1 cube

    for (int r = 2; r <= maxG; ++r) {
        if (__all(done)) break;
        if (!done) {
            int xlo = max(cx - r, 0), xhi = min(cx + r, Gx - 1);
            for (int zz = max(cz - r, 0); zz <= min(cz + r, Gz - 1); ++zz)
                for (int yy = max(cy - r, 0); yy <= min(cy + r, Gy - 1); ++yy) {
                    if (max(abs(zz - cz), abs(yy - cy)) == r) {
                        scan_cells(zz, yy, xlo, xhi);        // full edge row
                    } else {
                        if (cx - r >= 0)      scan_cells(zz, yy, cx - r, cx - r);
                        if (cx + r <= Gx - 1) scan_cells(zz, yy, cx + r, cx + r);
                    }
                }
            done = d2 < hmin2 * (float)(r * r);
        }
    }

    if (active) {
        float w0 = 1.0f / fmaxf(d0, 1e-16f);
        float w1 = 1.0f / fmaxf(d1, 1e-16f);
        float w2 = 1.0f / fmaxf(d2, 1e-16f);
        float s = w0 + w1 + w2;
        oidx[qi * 3 + 0] = j0; oidx[qi * 3 + 1] = j1; oidx[qi * 3 + 2] = j2;
        ow[qi * 4 + 0] = w0; ow[qi * 4 + 1] = w1; ow[qi * 4 + 2] = w2; ow[qi * 4 + 3] = s;
    }
}

// ---------- knn interpolate, float4-vectorized (32 thr/query) ----------
__global__ void k_interp(const float4* __restrict__ x4, const int* __restrict__ idx,
                         const float* __restrict__ w, float4* __restrict__ y4, int Nq) {
    int t = blockIdx.x * 256 + threadIdx.x;
    if (t >= Nq * 32) return;
    int j = t >> 5, c = t & 31;
    int i0 = idx[j * 3], i1 = idx[j * 3 + 1], i2 = idx[j * 3 + 2];
    float w0 = w[j * 4], w1 = w[j * 4 + 1], w2 = w[j * 4 + 2], s = w[j * 4 + 3];
    float inv = 1.0f / s;
    float4 a = x4[(size_t)i0 * 32 + c];
    float4 b = x4[(size_t)i1 * 32 + c];
    float4 d = x4[(size_t)i2 * 32 + c];
    float4 o;
    o.x = (w0 * a.x + w1 * b.x + w2 * d.x) * inv;
    o.y = (w0 * a.y + w1 * b.y + w2 * d.y) * inv;
    o.z = (w0 * a.z + w1 * b.z + w2 * d.z) * inv;
    o.w = (w0 * a.w + w1 * b.w + w2 * d.w) * inv;
    y4[(size_t)j * 32 + c] = o;
}

// ---------- output conv matmul (OC=5), row-scaled by dinv ----------
__global__ __launch_bounds__(256) void k_matmul5(const float* __restrict__ X, const float* __restrict__ P,
                                                 const float* __restrict__ W, const float* __restrict__ rs,
                                                 float* __restrict__ Y, int N) {
    __shared__ float xs[32][132];
    __shared__ float ws[131 * 5];
    int row0 = blockIdx.x * 32;
    for (int idx = threadIdx.x; idx < 131 * 5; idx += 256) ws[idx] = W[idx];
    for (int idx = threadIdx.x; idx < 32 * 128; idx += 256) {
        int r = idx >> 7, c = idx & 127;
        xs[r][c] = X[(size_t)(row0 + r) * 128 + c];
    }
    for (int idx = threadIdx.x; idx < 32 * 3; idx += 256) {
        int r = idx / 3, c = idx % 3;
        xs[r][128 + c] = P[(row0 + r) * 3 + c];
    }
    __syncthreads();
    int r = threadIdx.x >> 3;
    int c = threadIdx.x & 7;
    if (c < 5) {
        float acc = 0.0f;
        for (int i = 0; i < 131; ++i) acc = fmaf(xs[r][i], ws[i * 5 + c], acc);
        Y[(size_t)(row0 + r) * 5 + c] = acc * rs[row0 + r];
    }
}

extern "C" void kernel_launch(void* const* d_in, const int* in_sizes, int n_in,
                              void* d_out, int out_size, void* d_ws, size_t ws_size,
                              hipStream_t stream) {
    const float* latent = (const float*)d_in[0];
    const float* pos0   = (const float*)d_in[1];
    const float* pos1   = (const float*)d_in[2];
    const float* pos2   = (const float*)d_in[3];
    const float* W_lin  = (const float*)d_in[4];
    const float* b_lin  = (const float*)d_in[5];
    const float* W0 = (const float*)d_in[6];  const float* b0 = (const float*)d_in[7];
    const float* W1 = (const float*)d_in[8];  const float* b1 = (const float*)d_in[9];
    const float* W2 = (const float*)d_in[10]; const float* b2 = (const float*)d_in[11];
    const float* W3 = (const float*)d_in[12]; const float* b3 = (const float*)d_in[13];
    const float* W4 = (const float*)d_in[14]; const float* b4 = (const float*)d_in[15];
    const int* ei0 = (const int*)d_in[16];
    const int* ei1 = (const int*)d_in[17];
    const int* ei2 = (const int*)d_in[18];
    float* out = (float*)d_out;

    const int N0 = in_sizes[1] / 3, N1 = in_sizes[2] / 3, N2 = in_sizes[3] / 3;
    const int E0 = in_sizes[16] / 2, E1 = in_sizes[17] / 2, E2 = in_sizes[18] / 2;

    char* wsp = (char*)d_ws;
    auto alloc = [&](size_t bytes) {
        char* p = wsp;
        wsp += (bytes + 255) & ~size_t(255);
        return p;
    };
    float*    A       = (float*)alloc((size_t)N2 * 128 * 4);
    float*    Bb      = (float*)alloc((size_t)N2 * 128 * 4);
    float4*   tp0     = (float4*)alloc((size_t)N0 * 16);
    float4*   tp1     = (float4*)alloc((size_t)N1 * 16);
    float4*   tp2     = (float4*)alloc((size_t)N2 * 16);
    // per-level graph structures (built once, persist)
    float*    dv0     = (float*)alloc((size_t)N0 * 4);
    float*    dv1     = (float*)alloc((size_t)N1 * 4);
    float*    dv2     = (float*)alloc((size_t)N2 * 4);
    int*      cnt012  = (int*)  alloc((size_t)(N0 + N1 + N2) * 4);
    int*      cnt0 = cnt012, *cnt1 = cnt012 + N0, *cnt2 = cnt012 + N0 + N1;
    int*      rp0     = (int*)  alloc(((size_t)N0 + 1) * 4);
    int*      rp1     = (int*)  alloc(((size_t)N1 + 1) * 4);
    int*      rp2     = (int*)  alloc(((size_t)N2 + 1) * 4);
    int*      cur0    = (int*)  alloc((size_t)N0 * 4);
    int*      cur1    = (int*)  alloc((size_t)N1 * 4);
    int*      cur2    = (int*)  alloc((size_t)N2 * 4);
    int*      csr0    = (int*)  alloc((size_t)E0 * 4);
    int*      csr1    = (int*)  alloc((size_t)E1 * 4);
    int*      csr2    = (int*)  alloc((size_t)E2 * 4);
    int*      bsum    = (int*)  alloc(4096);
    float*    xw5     = (float*)alloc((size_t)N2 * 5 * 4);
    float*    bbp     = (float*)alloc((size_t)2 * BBOXBLK * 6 * 4);
    GP*       gps     = (GP*)   alloc(2 * sizeof(GP));
    int*      knncnt  = (int*)  alloc((size_t)4 * MAXC * 4);
    int*      knnrow  = (int*)  alloc((size_t)4 * (MAXC + 1) * 4);
    int*      knncur  = (int*)  alloc((size_t)4 * MAXC * 4);
    int*      gcell0  = (int*)  alloc((size_t)N0 * 4);
    int*      gcell1  = (int*)  alloc((size_t)N1 * 4);
    int*      qcell1  = (int*)  alloc((size_t)N1 * 4);
    int*      qcell2  = (int*)  alloc((size_t)N2 * 4);
    float4*   gpts0   = (float4*)alloc((size_t)N0 * 16);
    float4*   gpts1   = (float4*)alloc((size_t)N1 * 16);
    int*      qorder1 = (int*)  alloc((size_t)N1 * 4);
    int*      qorder2 = (int*)  alloc((size_t)N2 * 4);
    int*      kidx1   = (int*)  alloc((size_t)N1 * 3 * 4);
    float*    kw1     = (float*)alloc((size_t)N1 * 4 * 4);
    int*      kidx2   = (int*)  alloc((size_t)N2 * 3 * 4);
    float*    kw2     = (float*)alloc((size_t)N2 * 4 * 4);

    auto cdiv = [](int a, int b) { return (a + b - 1) / b; };

    // transforms (one launch)
    k_transform3<<<cdiv(N0 + N1 + N2, 256), 256, 0, stream>>>(pos0, tp0, N0, pos1, tp1, N1,
                                                              pos2, tp2, N2);

    // ---- both kNN levels fused ----
    {
        k_bbox2<<<dim3(BBOXBLK, 2), 256, 0, stream>>>(tp0, N0, tp1, N1, bbp);
        k_gridparams2<<<2, 64, 0, stream>>>(bbp, N0, N1, gps);
        hipMemsetAsync(knncnt, 0, (size_t)4 * MAXC * 4, stream);
        int tot = N0 + 2 * N1 + N2;
        k_cellid4<<<cdiv(tot, 256), 256, 0, stream>>>(tp0, N0, tp1, N1, tp2, N2,
                                                      gcell0, qcell1, gcell1, qcell2,
                                                      knncnt, gps);
        int nbc = cdiv(MAXC, 1024);
        k_scan1c<<<dim3(nbc, 4), 256, 0, stream>>>(knncnt, knnrow, bsum, nbc);
        k_scan2<<<4, 64, 0, stream>>>(bsum, nbc);
        k_scan3c<<<dim3(cdiv(MAXC, 256), 4), 256, 0, stream>>>(knnrow, knncur, bsum, nbc,
                                                               make_int4(N0, N1, N1, N2));
        k_scatter4<<<cdiv(tot, 256), 256, 0, stream>>>(tp0, N0, tp1, N1, tp2, N2,
                                                       gcell0, qcell1, gcell1, qcell2,
                                                       knncur, gpts0, gpts1, qorder1, qorder2);
        k_knn_grid2<<<cdiv(N1 + N2, 256), 256, 0, stream>>>(
            tp1, N1, qorder1, gpts0, knnrow, kidx1, kw1,
            tp2, N2, qorder2, gpts1, knnrow + 2 * (MAXC + 1), kidx2, kw2, gps);
    }

    // ---- all three graph builds batched ----
    {
        hipMemsetAsync(cnt012, 0, (size_t)(N0 + N1 + N2) * 4, stream);
        k_hist3<<<cdiv(E0 + E1 + E2, 256), 256, 0, stream>>>(ei0 + E0, E0, cnt0,
                                                             ei1 + E1, E1, cnt1,
                                                             ei2 + E2, E2, cnt2);
        int nbmax = cdiv(N2, 1024);
        k_scan1t<<<dim3(nbmax, 3), 256, 0, stream>>>(cnt0, rp0, dv0, N0,
                                                     cnt1, rp1, dv1, N1,
                                                     cnt2, rp2, dv2, N2, bsum, nbmax);
        k_scan2<<<3, 64, 0, stream>>>(bsum, nbmax);
        k_scan3t<<<dim3(cdiv(N2, 256), 3), 256, 0, stream>>>(rp0, cur0, E0, N0,
                                                             rp1, cur1, E1, N1,
                                                             rp2, cur2, E2, N2, bsum, nbmax);
        k_scatter3<<<cdiv(E0 + E1 + E2, 256), 256, 0, stream>>>(ei0, E0, cur0, csr0,
                                                                ei1, E1, cur1, csr1,
                                                                ei2, E2, cur2, csr2);
    }

    auto conv128 = [&](const float* x, const float* pos, int N,
                       const int* rp, const int* csr, const float* dv,
                       const float* W, const float* b, float* xws, float* outb) {
        k_matmul128<128, true, false, true><<<cdiv(N, 16), 256, 0, stream>>>(x, pos, W, nullptr, dv, xws, N);
        k_gather128<<<cdiv(N * 32, 256), 256, 0, stream>>>(rp, csr, (const float4*)xws, dv,
                                                           (const float4*)b, (float4*)outb, N);
    };

    // x = selu(latent @ W_lin + b_lin)  -> A
    k_matmul128<64, false, true, false><<<cdiv(N0, 16), 256, 0, stream>>>(latent, nullptr, W_lin, b_lin, nullptr, A, N0);

    // level 0: two convs
    conv128(A, pos0, N0, rp0, csr0, dv0, W0, b0, Bb, A);
    conv128(A, pos0, N0, rp0, csr0, dv0, W1, b1, Bb, A);

    // pool 0 -> 1
    k_interp<<<cdiv(N1 * 32, 256), 256, 0, stream>>>((const float4*)A, kidx1, kw1, (float4*)Bb, N1);

    // level 1 conv
    conv128(Bb, pos1, N1, rp1, csr1, dv1, W2, b2, A, Bb);

    // pool 1 -> 2
    k_interp<<<cdiv(N2 * 32, 256), 256, 0, stream>>>((const float4*)Bb, kidx2, kw2, (float4*)A, N2);

    // level 2 conv
    conv128(A, pos2, N2, rp2, csr2, dv2, W3, b3, Bb, A);

    // output conv (OC=5)
    k_matmul5<<<cdiv(N2, 32), 256, 0, stream>>>(A, pos2, W4, dv2, xw5, N2);
    k_gather5<<<cdiv(N2 * 8, 256), 256, 0, stream>>>(rp2, csr2, xw5, dv2, b4, out, N2);
}

// Round 15
// 926.148 us; speedup vs baseline: 1.1127x; 1.1127x over previous
//
#include <hip/hip_runtime.h>
#include <math.h>

#define TAN30f 0.57735026918962576f
#define SELU_SCALE 1.0507009873554805f
#define SELU_ALPHA 1.6732632423543772f

#define MAXC 65536   // max grid cells
#define MAXG 40
#define BBOXBLK 64

__device__ __forceinline__ float selu_f(float x) {
    return SELU_SCALE * (x > 0.0f ? x : SELU_ALPHA * expm1f(x));
}

struct GP {
    float ox, oy, oz, ihx, ihy, ihz, hmin2, pad;
    int Gx, Gy, Gz, maxG;
};

// ---------- dense matmul: Y[N,128] = concat(X[N,FIC], P[N,3]?) @ W ----------
template<int FIC, bool HAS_POS, bool BIAS_SELU, bool ROWSCALE>
__global__ __launch_bounds__(256) void k_matmul128(
    const float* __restrict__ X, const float* __restrict__ P,
    const float* __restrict__ W, const float* __restrict__ bias,
    const float* __restrict__ rs,
    float* __restrict__ Y, int N)
{
    constexpr int ICT = FIC + (HAS_POS ? 3 : 0);
    __shared__ float xs[16][ICT + 1];
    int row0 = blockIdx.x * 16;

    for (int idx = threadIdx.x; idx < 16 * FIC; idx += 256) {
        int r = idx / FIC, c = idx % FIC;
        int gr = row0 + r;
        xs[r][c] = (gr < N) ? X[gr * FIC + c] : 0.0f;
    }
    if (HAS_POS) {
        for (int idx = threadIdx.x; idx < 16 * 3; idx += 256) {
            int r = idx / 3, c = idx % 3;
            int gr = row0 + r;
            xs[r][FIC + c] = (gr < N) ? P[gr * 3 + c] : 0.0f;
        }
    }
    __syncthreads();

    int col = threadIdx.x & 127;
    int half = threadIdx.x >> 7;
    float acc[8];
#pragma unroll
    for (int r = 0; r < 8; ++r) acc[r] = 0.0f;

#pragma unroll 4
    for (int i = 0; i < ICT; ++i) {
        float wv = W[i * 128 + col];
#pragma unroll
        for (int r = 0; r < 8; ++r)
            acc[r] = fmaf(xs[half * 8 + r][i], wv, acc[r]);
    }

    float bv = BIAS_SELU ? bias[col] : 0.0f;
#pragma unroll
    for (int r = 0; r < 8; ++r) {
        int gr = row0 + half * 8 + r;
        if (gr < N) {
            float v = acc[r];
            if (BIAS_SELU) v = selu_f(v + bv);
            if (ROWSCALE) v *= rs[gr];
            Y[gr * 128 + col] = v;
        }
    }
}

// ---------- batched triple graph build (all levels at once) ----------
__global__ void k_hist3(const int* __restrict__ c0, int E0, int* __restrict__ n0,
                        const int* __restrict__ c1, int E1, int* __restrict__ n1,
                        const int* __restrict__ c2, int E2, int* __restrict__ n2) {
    int i = blockIdx.x * 256 + threadIdx.x;
    if (i < E0) atomicAdd(&n0[c0[i]], 1);
    else if (i < E0 + E1) atomicAdd(&n1[c1[i - E0]], 1);
    else if (i < E0 + E1 + E2) atomicAdd(&n2[c2[i - E0 - E1]], 1);
}

__global__ __launch_bounds__(256) void k_scan1t(
    const int* __restrict__ in0, int* __restrict__ out0, float* __restrict__ dva, int n0a,
    const int* __restrict__ in1, int* __restrict__ out1, float* __restrict__ dvb, int n1a,
    const int* __restrict__ in2, int* __restrict__ out2, float* __restrict__ dvc, int n2a,
    int* __restrict__ bsum, int nbmax)
{
    int y = blockIdx.y;
    const int* in = y == 0 ? in0 : (y == 1 ? in1 : in2);
    int* out = y == 0 ? out0 : (y == 1 ? out1 : out2);
    float* dv = y == 0 ? dva : (y == 1 ? dvb : dvc);
    int n = y == 0 ? n0a : (y == 1 ? n1a : n2a);
    __shared__ int s[256];
    int tid = threadIdx.x;
    int base = blockIdx.x * 1024 + tid * 4;
    int a[4];
#pragma unroll
    for (int k = 0; k < 4; ++k) a[k] = (base + k < n) ? in[base + k] : 0;
#pragma unroll
    for (int k = 0; k < 4; ++k)
        if (base + k < n) dv[base + k] = rsqrtf((float)a[k] + 1.0f);
    int t = a[0] + a[1] + a[2] + a[3];
    s[tid] = t;
    __syncthreads();
    for (int off = 1; off < 256; off <<= 1) {
        int x = (tid >= off) ? s[tid - off] : 0;
        __syncthreads();
        s[tid] += x;
        __syncthreads();
    }
    int run = s[tid] - t;
#pragma unroll
    for (int k = 0; k < 4; ++k) {
        if (base + k < n) out[base + k] = run;
        run += a[k];
    }
    if (tid == 255) bsum[y * nbmax + blockIdx.x] = s[255];
}

__global__ void k_scan2(int* __restrict__ bsum, int nb) {
    if (threadIdx.x == 0) {
        int* b = bsum + blockIdx.x * nb;
        int run = 0;
        for (int i = 0; i < nb; ++i) { int v = b[i]; b[i] = run; run += v; }
    }
}

__global__ void k_scan3t(int* __restrict__ rp0, int* __restrict__ cu0, int E0, int n0a,
                         int* __restrict__ rp1, int* __restrict__ cu1, int E1, int n1a,
                         int* __restrict__ rp2, int* __restrict__ cu2, int E2, int n2a,
                         const int* __restrict__ bsum, int nbmax) {
    int y = blockIdx.y;
    int* rp = y == 0 ? rp0 : (y == 1 ? rp1 : rp2);
    int* cu = y == 0 ? cu0 : (y == 1 ? cu1 : cu2);
    int E = y == 0 ? E0 : (y == 1 ? E1 : E2);
    int n = y == 0 ? n0a : (y == 1 ? n1a : n2a);
    const int* bs = bsum + y * nbmax;
    int i = blockIdx.x * 256 + threadIdx.x;
    if (i < n) {
        int v = rp[i] + bs[i >> 10];
        rp[i] = v;
        cu[i] = v;
    }
    if (i == 0) rp[n] = E;
}

__global__ void k_scatter3(const int* __restrict__ ei0, int E0, int* __restrict__ cu0, int* __restrict__ cs0,
                           const int* __restrict__ ei1, int E1, int* __restrict__ cu1, int* __restrict__ cs1,
                           const int* __restrict__ ei2, int E2, int* __restrict__ cu2, int* __restrict__ cs2) {
    int i = blockIdx.x * 256 + threadIdx.x;
    const int* ei; int E; int* cur; int* csr; int e;
    if (i < E0)               { ei = ei0; E = E0; cur = cu0; csr = cs0; e = i; }
    else if (i < E0 + E1)     { ei = ei1; E = E1; cur = cu1; csr = cs1; e = i - E0; }
    else if (i < E0 + E1 + E2){ ei = ei2; E = E2; cur = cu2; csr = cs2; e = i - E0 - E1; }
    else return;
    int r = ei[e], c = ei[E + e];
    int p = atomicAdd(&cur[c], 1);
    csr[p] = r;
}

// ---------- CSR gather aggregation, float4-vectorized (32 thr/node) ----------
__global__ __launch_bounds__(256) void k_gather128(
    const int* __restrict__ rowptr, const int* __restrict__ csr,
    const float4* __restrict__ xws4, const float* __restrict__ dv,
    const float4* __restrict__ bias4, float4* __restrict__ out4, int N)
{
    int t = blockIdx.x * 256 + threadIdx.x;
    int node = t >> 5, c4 = t & 31;
    if (node >= N) return;
    int s = rowptr[node], e = rowptr[node + 1];
    float4 acc = xws4[(size_t)node * 32 + c4];  // self loop (already *dinv[node])
    for (int i = s; i < e; ++i) {
        int src = csr[i];
        float4 v = xws4[(size_t)src * 32 + c4];
        acc.x += v.x; acc.y += v.y; acc.z += v.z; acc.w += v.w;
    }
    float d = dv[node];
    float4 b = bias4[c4];
    float4 o;
    o.x = selu_f(fmaf(acc.x, d, b.x));
    o.y = selu_f(fmaf(acc.y, d, b.y));
    o.z = selu_f(fmaf(acc.z, d, b.z));
    o.w = selu_f(fmaf(acc.w, d, b.w));
    out4[(size_t)node * 32 + c4] = o;
}

__global__ __launch_bounds__(256) void k_gather5(
    const int* __restrict__ rowptr, const int* __restrict__ csr,
    const float* __restrict__ xws, const float* __restrict__ dv,
    const float* __restrict__ bias, float* __restrict__ out, int N)
{
    int t = blockIdx.x * 256 + threadIdx.x;
    int node = t >> 3, ch = t & 7;
    if (node >= N || ch >= 5) return;
    int s = rowptr[node], e = rowptr[node + 1];
    float acc = xws[(size_t)node * 5 + ch];
    for (int i = s; i < e; ++i) {
        int src = csr[i];
        acc += xws[(size_t)src * 5 + ch];
    }
    out[(size_t)node * 5 + ch] = acc * dv[node] + bias[ch];
}

// ---------- onera transform (all 3 levels fused); emits {x,y,z,|p|^2} ----------
__global__ void k_transform3(const float* __restrict__ p0, float4* __restrict__ t0, int n0,
                             const float* __restrict__ p1, float4* __restrict__ t1, int n1,
                             const float* __restrict__ p2, float4* __restrict__ t2, int n2) {
    int i = blockIdx.x * 256 + threadIdx.x;
    const float* pos; float4* tp; int li;
    if (i < n0) { pos = p0; tp = t0; li = i; }
    else if (i < n0 + n1) { pos = p1; tp = t1; li = i - n0; }
    else if (i < n0 + n1 + n2) { pos = p2; tp = t2; li = i - n0 - n1; }
    else return;
    float x = pos[li * 3 + 0], y = pos[li * 3 + 1], z = pos[li * 3 + 2];
    float nx = x - TAN30f * y;
    float f = 1.0f + (1.0f / 0.56f - 1.0f) * (y / 1.1963f);
    float X = nx * f, Y = y * f, Z = z * f;
    tp[li] = make_float4(X, Y, Z, (X * X + Y * Y) + Z * Z);
}

// ---------- spatial grid kNN (both levels fused) ----------
__global__ __launch_bounds__(256) void k_bbox2(const float4* __restrict__ tpa, int na,
                                               const float4* __restrict__ tpb, int nb,
                                               float* __restrict__ bbp) {
    const float4* tp = blockIdx.y ? tpb : tpa;
    int n = blockIdx.y ? nb : na;
    __shared__ float red[6][256];
    float mn0 = 3.4e38f, mn1 = 3.4e38f, mn2 = 3.4e38f;
    float mx0 = -3.4e38f, mx1 = -3.4e38f, mx2 = -3.4e38f;
    for (int i = blockIdx.x * 256 + threadIdx.x; i < n; i += gridDim.x * 256) {
        float4 t = tp[i];
        mn0 = fminf(mn0, t.x); mx0 = fmaxf(mx0, t.x);
        mn1 = fminf(mn1, t.y); mx1 = fmaxf(mx1, t.y);
        mn2 = fminf(mn2, t.z); mx2 = fmaxf(mx2, t.z);
    }
    int tid = threadIdx.x;
    red[0][tid] = mn0; red[1][tid] = mn1; red[2][tid] = mn2;
    red[3][tid] = mx0; red[4][tid] = mx1; red[5][tid] = mx2;
    __syncthreads();
    for (int off = 128; off > 0; off >>= 1) {
        if (tid < off) {
#pragma unroll
            for (int k = 0; k < 3; ++k) {
                red[k][tid] = fminf(red[k][tid], red[k][tid + off]);
                red[3 + k][tid] = fmaxf(red[3 + k][tid], red[3 + k][tid + off]);
            }
        }
        __syncthreads();
    }
    if (tid == 0) {
        float* o = bbp + (blockIdx.y * BBOXBLK + blockIdx.x) * 6;
#pragma unroll
        for (int k = 0; k < 3; ++k) {
            o[k] = red[k][0];
            o[3 + k] = red[3 + k][0];
        }
    }
}

__global__ void k_gridparams2(const float* __restrict__ bbp, int na, int nb,
                              GP* __restrict__ gps) {
    if (threadIdx.x != 0) return;
    int set = blockIdx.x;
    const float* bp = bbp + set * BBOXBLK * 6;
    int n = set ? nb : na;
    GP* gp = gps + set;
    float mn[3] = {3.4e38f, 3.4e38f, 3.4e38f};
    float mx[3] = {-3.4e38f, -3.4e38f, -3.4e38f};
    for (int i = 0; i < BBOXBLK; ++i) {
#pragma unroll
        for (int k = 0; k < 3; ++k) {
            mn[k] = fminf(mn[k], bp[i * 6 + k]);
            mx[k] = fmaxf(mx[k], bp[i * 6 + 3 + k]);
        }
    }
    float e[3], o[3];
#pragma unroll
    for (int k = 0; k < 3; ++k) {
        float ext = fmaxf(mx[k] - mn[k], 1e-6f);
        float padv = ext * 1e-4f + 1e-6f;
        o[k] = mn[k] - padv;
        e[k] = ext + 2.0f * padv;
    }
    float T = (float)n * 0.2f;  // target ~5 pts/cell
    float s = cbrtf(T / (e[0] * e[1] * e[2]));
    int G[3];
#pragma unroll
    for (int k = 0; k < 3; ++k) {
        int g = (int)ceilf(e[k] * s);
        G[k] = g < 1 ? 1 : (g > MAXG ? MAXG : g);
    }
    float h[3];
#pragma unroll
    for (int k = 0; k < 3; ++k) h[k] = e[k] / (float)G[k];
    float hmin = fminf(h[0], fminf(h[1], h[2]));
    gp->ox = o[0]; gp->oy = o[1]; gp->oz = o[2];
    gp->ihx = (float)G[0] / e[0]; gp->ihy = (float)G[1] / e[1]; gp->ihz = (float)G[2] / e[2];
    gp->hmin2 = hmin * hmin;
    gp->Gx = G[0]; gp->Gy = G[1]; gp->Gz = G[2];
    gp->maxG = max(G[0], max(G[1], G[2]));
}

__device__ __forceinline__ int cell_of(float4 t, const GP* gp) {
    int cx = min(max((int)((t.x - gp->ox) * gp->ihx), 0), gp->Gx - 1);
    int cy = min(max((int)((t.y - gp->oy) * gp->ihy), 0), gp->Gy - 1);
    int cz = min(max((int)((t.z - gp->oz) * gp->ihz), 0), gp->Gz - 1);
    return (cz * gp->Gy + cy) * gp->Gx + cx;
}

// 4 segments: ref0 (tp0,gp0) | q1 (tp1,gp0) | ref1 (tp1,gp1) | q2 (tp2,gp1)
__global__ void k_cellid4(const float4* __restrict__ tp0, int N0,
                          const float4* __restrict__ tp1, int N1,
                          const float4* __restrict__ tp2, int N2,
                          int* __restrict__ gcell0, int* __restrict__ qcell1,
                          int* __restrict__ gcell1, int* __restrict__ qcell2,
                          int* __restrict__ cnt, const GP* __restrict__ gps) {
    int i = blockIdx.x * 256 + threadIdx.x;
    const float4* tp; const GP* gp; int* cellout; int* cn; int li;
    if (i < N0)                { tp = tp0; gp = gps;     cellout = gcell0; cn = cnt;            li = i; }
    else if (i < N0 + N1)      { tp = tp1; gp = gps;     cellout = qcell1; cn = cnt + MAXC;     li = i - N0; }
    else if (i < N0 + 2 * N1)  { tp = tp1; gp = gps + 1; cellout = gcell1; cn = cnt + 2 * MAXC; li = i - N0 - N1; }
    else if (i < N0 + 2 * N1 + N2) { tp = tp2; gp = gps + 1; cellout = qcell2; cn = cnt + 3 * MAXC; li = i - N0 - 2 * N1; }
    else return;
    int cid = cell_of(tp[li], gp);
    cellout[li] = cid;
    atomicAdd(&cn[cid], 1);
}

__global__ __launch_bounds__(256) void k_scan1c(const int* __restrict__ cnt,
                                                int* __restrict__ row,
                                                int* __restrict__ bsum, int nb) {
    const int* in = cnt + blockIdx.y * MAXC;
    int* out = row + blockIdx.y * (MAXC + 1);
    __shared__ int s[256];
    int tid = threadIdx.x;
    int base = blockIdx.x * 1024 + tid * 4;
    int a[4];
#pragma unroll
    for (int k = 0; k < 4; ++k) a[k] = (base + k < MAXC) ? in[base + k] : 0;
    int t = a[0] + a[1] + a[2] + a[3];
    s[tid] = t;
    __syncthreads();
    for (int off = 1; off < 256; off <<= 1) {
        int x = (tid >= off) ? s[tid - off] : 0;
        __syncthreads();
        s[tid] += x;
        __syncthreads();
    }
    int run = s[tid] - t;
#pragma unroll
    for (int k = 0; k < 4; ++k) {
        if (base + k < MAXC) out[base + k] = run;
        run += a[k];
    }
    if (tid == 255) bsum[blockIdx.y * nb + blockIdx.x] = s[255];
}

__global__ void k_scan3c(int* __restrict__ row, int* __restrict__ cur,
                         const int* __restrict__ bsum, int nb, int4 E4) {
    int y = blockIdx.y;
    int* rp = row + y * (MAXC + 1);
    int* cu = cur + y * MAXC;
    const int* bs = bsum + y * nb;
    int E = (y == 0) ? E4.x : (y == 1) ? E4.y : (y == 2) ? E4.z : E4.w;
    int i = blockIdx.x * 256 + threadIdx.x;
    if (i < MAXC) {
        int v = rp[i] + bs[i >> 10];
        rp[i] = v;
        cu[i] = v;
    }
    if (i == 0) rp[MAXC] = E;
}

__global__ void k_scatter4(const float4* __restrict__ tp0, int N0,
                           const float4* __restrict__ tp1, int N1,
                           const float4* __restrict__ tp2, int N2,
                           const int* __restrict__ gcell0, const int* __restrict__ qcell1,
                           const int* __restrict__ gcell1, const int* __restrict__ qcell2,
                           int* __restrict__ cur,
                           float4* __restrict__ gpts0, float4* __restrict__ gpts1,
                           int* __restrict__ qorder1, int* __restrict__ qorder2) {
    int i = blockIdx.x * 256 + threadIdx.x;
    if (i < N0) {
        int p = atomicAdd(&cur[gcell0[i]], 1);
        float4 t = tp0[i];
        t.w = __int_as_float(i);
        gpts0[p] = t;
    } else if (i < N0 + N1) {
        int j = i - N0;
        int p = atomicAdd(&cur[MAXC + qcell1[j]], 1);
        qorder1[p] = j;
    } else if (i < N0 + 2 * N1) {
        int j = i - N0 - N1;
        int p = atomicAdd(&cur[2 * MAXC + gcell1[j]], 1);
        float4 t = tp1[j];
        t.w = __int_as_float(j);
        gpts1[p] = t;
    } else if (i < N0 + 2 * N1 + N2) {
        int j = i - N0 - 2 * N1;
        int p = atomicAdd(&cur[3 * MAXC + qcell2[j]], 1);
        qorder2[p] = j;
    }
}

// Both levels' searches in one launch; point scan unrolled x4 (proven
// R13 config — x8 spills to scratch, WRITE_SIZE 10->32 MB, regressed).
__global__ __launch_bounds__(256) void k_knn_grid2(
    const float4* __restrict__ tpq1, int N1, const int* __restrict__ qorder1,
    const float4* __restrict__ gpts0, const int* __restrict__ crow0,
    int* __restrict__ oidx1, float* __restrict__ ow1,
    const float4* __restrict__ tpq2, int N2, const int* __restrict__ qorder2,
    const float4* __restrict__ gpts1, const int* __restrict__ crow1,
    int* __restrict__ oidx2, float* __restrict__ ow2,
    const GP* __restrict__ gps)
{
    int t = blockIdx.x * 256 + threadIdx.x;
    const float4* tpq; const int* qord; const float4* gpts; const int* crow;
    const GP* gp; int* oidx; float* ow; int slot; int Nq;
    if (t < N1) {
        tpq = tpq1; qord = qorder1; gpts = gpts0; crow = crow0;
        gp = gps; oidx = oidx1; ow = ow1; slot = t; Nq = N1;
    } else {
        tpq = tpq2; qord = qorder2; gpts = gpts1; crow = crow1;
        gp = gps + 1; oidx = oidx2; ow = ow2; slot = t - N1; Nq = N2;
    }
    bool active = slot < Nq;
    int qi = active ? qord[slot] : 0;

    float ox = gp->ox, oy = gp->oy, oz = gp->oz;
    float ihx = gp->ihx, ihy = gp->ihy, ihz = gp->ihz;
    float hmin2 = gp->hmin2;
    int Gx = gp->Gx, Gy = gp->Gy, Gz = gp->Gz, maxG = gp->maxG;

    float qx = 0, qy = 0, qz = 0, q2 = 0;
    if (active) { float4 tq = tpq[qi]; qx = tq.x; qy = tq.y; qz = tq.z; q2 = tq.w; }
    int cx = min(max((int)((qx - ox) * ihx), 0), Gx - 1);
    int cy = min(max((int)((qy - oy) * ihy), 0), Gy - 1);
    int cz = min(max((int)((qz - oz) * ihz), 0), Gz - 1);

    float d0 = 3.4e38f, d1 = 3.4e38f, d2 = 3.4e38f;
    int j0 = 0x7FFFFFFF, j1 = 0x7FFFFFFF, j2 = 0x7FFFFFFF;

    auto insert = [&](float d, int id) {
        // lexicographic (d, id) — matches top_k tie order
        if (d < d2 || (d == d2 && id < j2)) {
            if (d < d1 || (d == d1 && id < j1)) {
                d2 = d1; j2 = j1;
                if (d < d0 || (d == d0 && id < j0)) {
                    d1 = d0; j1 = j0; d0 = d; j0 = id;
                } else { d1 = d; j1 = id; }
            } else { d2 = d; j2 = id; }
        }
    };
    auto proc = [&](float4 p) {
        int id = __float_as_int(p.w);
        float px2 = fmaf(p.z, p.z, fmaf(p.y, p.y, p.x * p.x));
        float dot = fmaf(p.z, qz, fmaf(p.y, qy, p.x * qx));
        float d = (q2 - 2.0f * dot) + px2;
        insert(d, id);
    };
    auto scan_range = [&](int s, int e) {
        int i = s;
        for (; i + 3 < e; i += 4) {
            float4 pa = gpts[i], pb = gpts[i + 1], pc = gpts[i + 2], pd = gpts[i + 3];
            proc(pa); proc(pb); proc(pc); proc(pd);
        }
        for (; i < e; ++i) { float4 p = gpts[i]; proc(p); }
    };
    auto scan_cells = [&](int zz, int yy, int xlo, int xhi) {
        int base = (zz * Gy + yy) * Gx;
        scan_range(crow[base + xlo], crow[base + xhi + 1]);
    };

    {
        int xlo = max(cx - 1, 0), xhi = min(cx + 1, Gx - 1);
        int rs[9], re[9];
#pragma unroll
        for (int k = 0; k < 9; ++k) {
            int zz = cz + k / 3 - 1, yy = cy + k % 3 - 1;
            bool ok = active && zz >= 0 && zz < Gz && yy >= 0 && yy < Gy;
            int base = ok ? (zz * Gy + yy) * Gx : 0;
            int a = crow[base + (ok ? xlo : 0)];
            int b = crow[base + (ok ? xhi + 1 : 0)];
            rs[k] = ok ? a : 0;
            re[k] = ok ? b : 0;
        }
#pragma unroll
        for (int k = 0; k < 9; ++k) scan_range(rs[k], re[k]);
    }
    bool done = !active || (d2 < hmin2);   // guarantee radius 1*hmin after r=1 cube

    for (int r = 2; r <= maxG; ++r) {
        if (__all(done)) break;
        if (!done) {
            int xlo = max(cx - r, 0), xhi = min(cx + r, Gx - 1);
            for (int zz = max(cz - r, 0); zz <= min(cz + r, Gz - 1); ++zz)
                for (int yy = max(cy - r, 0); yy <= min(cy + r, Gy - 1); ++yy) {
                    if (max(abs(zz - cz), abs(yy - cy)) == r) {
                        scan_cells(zz, yy, xlo, xhi);        // full edge row
                    } else {
                        if (cx - r >= 0)      scan_cells(zz, yy, cx - r, cx - r);
                        if (cx + r <= Gx - 1) scan_cells(zz, yy, cx + r, cx + r);
                    }
                }
            done = d2 < hmin2 * (float)(r * r);
        }
    }

    if (active) {
        float w0 = 1.0f / fmaxf(d0, 1e-16f);
        float w1 = 1.0f / fmaxf(d1, 1e-16f);
        float w2 = 1.0f / fmaxf(d2, 1e-16f);
        float s = w0 + w1 + w2;
        oidx[qi * 3 + 0] = j0; oidx[qi * 3 + 1] = j1; oidx[qi * 3 + 2] = j2;
        ow[qi * 4 + 0] = w0; ow[qi * 4 + 1] = w1; ow[qi * 4 + 2] = w2; ow[qi * 4 + 3] = s;
    }
}

// ---------- knn interpolate, float4-vectorized (32 thr/query) ----------
__global__ void k_interp(const float4* __restrict__ x4, const int* __restrict__ idx,
                         const float* __restrict__ w, float4* __restrict__ y4, int Nq) {
    int t = blockIdx.x * 256 + threadIdx.x;
    if (t >= Nq * 32) return;
    int j = t >> 5, c = t & 31;
    int i0 = idx[j * 3], i1 = idx[j * 3 + 1], i2 = idx[j * 3 + 2];
    float w0 = w[j * 4], w1 = w[j * 4 + 1], w2 = w[j * 4 + 2], s = w[j * 4 + 3];
    float inv = 1.0f / s;
    float4 a = x4[(size_t)i0 * 32 + c];
    float4 b = x4[(size_t)i1 * 32 + c];
    float4 d = x4[(size_t)i2 * 32 + c];
    float4 o;
    o.x = (w0 * a.x + w1 * b.x + w2 * d.x) * inv;
    o.y = (w0 * a.y + w1 * b.y + w2 * d.y) * inv;
    o.z = (w0 * a.z + w1 * b.z + w2 * d.z) * inv;
    o.w = (w0 * a.w + w1 * b.w + w2 * d.w) * inv;
    y4[(size_t)j * 32 + c] = o;
}

// ---------- output conv matmul (OC=5), row-scaled by dinv ----------
__global__ __launch_bounds__(256) void k_matmul5(const float* __restrict__ X, const float* __restrict__ P,
                                                 const float* __restrict__ W, const float* __restrict__ rs,
                                                 float* __restrict__ Y, int N) {
    __shared__ float xs[32][132];
    __shared__ float ws[131 * 5];
    int row0 = blockIdx.x * 32;
    for (int idx = threadIdx.x; idx < 131 * 5; idx += 256) ws[idx] = W[idx];
    for (int idx = threadIdx.x; idx < 32 * 128; idx += 256) {
        int r = idx >> 7, c = idx & 127;
        xs[r][c] = X[(size_t)(row0 + r) * 128 + c];
    }
    for (int idx = threadIdx.x; idx < 32 * 3; idx += 256) {
        int r = idx / 3, c = idx % 3;
        xs[r][128 + c] = P[(row0 + r) * 3 + c];
    }
    __syncthreads();
    int r = threadIdx.x >> 3;
    int c = threadIdx.x & 7;
    if (c < 5) {
        float acc = 0.0f;
        for (int i = 0; i < 131; ++i) acc = fmaf(xs[r][i], ws[i * 5 + c], acc);
        Y[(size_t)(row0 + r) * 5 + c] = acc * rs[row0 + r];
    }
}

extern "C" void kernel_launch(void* const* d_in, const int* in_sizes, int n_in,
                              void* d_out, int out_size, void* d_ws, size_t ws_size,
                              hipStream_t stream) {
    const float* latent = (const float*)d_in[0];
    const float* pos0   = (const float*)d_in[1];
    const float* pos1   = (const float*)d_in[2];
    const float* pos2   = (const float*)d_in[3];
    const float* W_lin  = (const float*)d_in[4];
    const float* b_lin  = (const float*)d_in[5];
    const float* W0 = (const float*)d_in[6];  const float* b0 = (const float*)d_in[7];
    const float* W1 = (const float*)d_in[8];  const float* b1 = (const float*)d_in[9];
    const float* W2 = (const float*)d_in[10]; const float* b2 = (const float*)d_in[11];
    const float* W3 = (const float*)d_in[12]; const float* b3 = (const float*)d_in[13];
    const float* W4 = (const float*)d_in[14]; const float* b4 = (const float*)d_in[15];
    const int* ei0 = (const int*)d_in[16];
    const int* ei1 = (const int*)d_in[17];
    const int* ei2 = (const int*)d_in[18];
    float* out = (float*)d_out;

    const int N0 = in_sizes[1] / 3, N1 = in_sizes[2] / 3, N2 = in_sizes[3] / 3;
    const int E0 = in_sizes[16] / 2, E1 = in_sizes[17] / 2, E2 = in_sizes[18] / 2;

    char* wsp = (char*)d_ws;
    auto alloc = [&](size_t bytes) {
        char* p = wsp;
        wsp += (bytes + 255) & ~size_t(255);
        return p;
    };
    float*    A       = (float*)alloc((size_t)N2 * 128 * 4);
    float*    Bb      = (float*)alloc((size_t)N2 * 128 * 4);
    float4*   tp0     = (float4*)alloc((size_t)N0 * 16);
    float4*   tp1     = (float4*)alloc((size_t)N1 * 16);
    float4*   tp2     = (float4*)alloc((size_t)N2 * 16);
    // per-level graph structures (built once, persist)
    float*    dv0     = (float*)alloc((size_t)N0 * 4);
    float*    dv1     = (float*)alloc((size_t)N1 * 4);
    float*    dv2     = (float*)alloc((size_t)N2 * 4);
    int*      cnt012  = (int*)  alloc((size_t)(N0 + N1 + N2) * 4);
    int*      cnt0 = cnt012, *cnt1 = cnt012 + N0, *cnt2 = cnt012 + N0 + N1;
    int*      rp0     = (int*)  alloc(((size_t)N0 + 1) * 4);
    int*      rp1     = (int*)  alloc(((size_t)N1 + 1) * 4);
    int*      rp2     = (int*)  alloc(((size_t)N2 + 1) * 4);
    int*      cur0    = (int*)  alloc((size_t)N0 * 4);
    int*      cur1    = (int*)  alloc((size_t)N1 * 4);
    int*      cur2    = (int*)  alloc((size_t)N2 * 4);
    int*      csr0    = (int*)  alloc((size_t)E0 * 4);
    int*      csr1    = (int*)  alloc((size_t)E1 * 4);
    int*      csr2    = (int*)  alloc((size_t)E2 * 4);
    int*      bsum    = (int*)  alloc(4096);
    float*    xw5     = (float*)alloc((size_t)N2 * 5 * 4);
    float*    bbp     = (float*)alloc((size_t)2 * BBOXBLK * 6 * 4);
    GP*       gps     = (GP*)   alloc(2 * sizeof(GP));
    int*      knncnt  = (int*)  alloc((size_t)4 * MAXC * 4);
    int*      knnrow  = (int*)  alloc((size_t)4 * (MAXC + 1) * 4);
    int*      knncur  = (int*)  alloc((size_t)4 * MAXC * 4);
    int*      gcell0  = (int*)  alloc((size_t)N0 * 4);
    int*      gcell1  = (int*)  alloc((size_t)N1 * 4);
    int*      qcell1  = (int*)  alloc((size_t)N1 * 4);
    int*      qcell2  = (int*)  alloc((size_t)N2 * 4);
    float4*   gpts0   = (float4*)alloc((size_t)N0 * 16);
    float4*   gpts1   = (float4*)alloc((size_t)N1 * 16);
    int*      qorder1 = (int*)  alloc((size_t)N1 * 4);
    int*      qorder2 = (int*)  alloc((size_t)N2 * 4);
    int*      kidx1   = (int*)  alloc((size_t)N1 * 3 * 4);
    float*    kw1     = (float*)alloc((size_t)N1 * 4 * 4);
    int*      kidx2   = (int*)  alloc((size_t)N2 * 3 * 4);
    float*    kw2     = (float*)alloc((size_t)N2 * 4 * 4);

    auto cdiv = [](int a, int b) { return (a + b - 1) / b; };

    // transforms (one launch)
    k_transform3<<<cdiv(N0 + N1 + N2, 256), 256, 0, stream>>>(pos0, tp0, N0, pos1, tp1, N1,
                                                              pos2, tp2, N2);

    // ---- both kNN levels fused ----
    {
        k_bbox2<<<dim3(BBOXBLK, 2), 256, 0, stream>>>(tp0, N0, tp1, N1, bbp);
        k_gridparams2<<<2, 64, 0, stream>>>(bbp, N0, N1, gps);
        hipMemsetAsync(knncnt, 0, (size_t)4 * MAXC * 4, stream);
        int tot = N0 + 2 * N1 + N2;
        k_cellid4<<<cdiv(tot, 256), 256, 0, stream>>>(tp0, N0, tp1, N1, tp2, N2,
                                                      gcell0, qcell1, gcell1, qcell2,
                                                      knncnt, gps);
        int nbc = cdiv(MAXC, 1024);
        k_scan1c<<<dim3(nbc, 4), 256, 0, stream>>>(knncnt, knnrow, bsum, nbc);
        k_scan2<<<4, 64, 0, stream>>>(bsum, nbc);
        k_scan3c<<<dim3(cdiv(MAXC, 256), 4), 256, 0, stream>>>(knnrow, knncur, bsum, nbc,
                                                               make_int4(N0, N1, N1, N2));
        k_scatter4<<<cdiv(tot, 256), 256, 0, stream>>>(tp0, N0, tp1, N1, tp2, N2,
                                                       gcell0, qcell1, gcell1, qcell2,
                                                       knncur, gpts0, gpts1, qorder1, qorder2);
        k_knn_grid2<<<cdiv(N1 + N2, 256), 256, 0, stream>>>(
            tp1, N1, qorder1, gpts0, knnrow, kidx1, kw1,
            tp2, N2, qorder2, gpts1, knnrow + 2 * (MAXC + 1), kidx2, kw2, gps);
    }

    // ---- all three graph builds batched ----
    {
        hipMemsetAsync(cnt012, 0, (size_t)(N0 + N1 + N2) * 4, stream);
        k_hist3<<<cdiv(E0 + E1 + E2, 256), 256, 0, stream>>>(ei0 + E0, E0, cnt0,
                                                             ei1 + E1, E1, cnt1,
                                                             ei2 + E2, E2, cnt2);
        int nbmax = cdiv(N2, 1024);
        k_scan1t<<<dim3(nbmax, 3), 256, 0, stream>>>(cnt0, rp0, dv0, N0,
                                                     cnt1, rp1, dv1, N1,
                                                     cnt2, rp2, dv2, N2, bsum, nbmax);
        k_scan2<<<3, 64, 0, stream>>>(bsum, nbmax);
        k_scan3t<<<dim3(cdiv(N2, 256), 3), 256, 0, stream>>>(rp0, cur0, E0, N0,
                                                             rp1, cur1, E1, N1,
                                                             rp2, cur2, E2, N2, bsum, nbmax);
        k_scatter3<<<cdiv(E0 + E1 + E2, 256), 256, 0, stream>>>(ei0, E0, cur0, csr0,
                                                                ei1, E1, cur1, csr1,
                                                                ei2, E2, cur2, csr2);
    }

    auto conv128 = [&](const float* x, const float* pos, int N,
                       const int* rp, const int* csr, const float* dv,
                       const float* W, const float* b, float* xws, float* outb) {
        k_matmul128<128, true, false, true><<<cdiv(N, 16), 256, 0, stream>>>(x, pos, W, nullptr, dv, xws, N);
        k_gather128<<<cdiv(N * 32, 256), 256, 0, stream>>>(rp, csr, (const float4*)xws, dv,
                                                           (const float4*)b, (float4*)outb, N);
    };

    // x = selu(latent @ W_lin + b_lin)  -> A
    k_matmul128<64, false, true, false><<<cdiv(N0, 16), 256, 0, stream>>>(latent, nullptr, W_lin, b_lin, nullptr, A, N0);

    // level 0: two convs
    conv128(A, pos0, N0, rp0, csr0, dv0, W0, b0, Bb, A);
    conv128(A, pos0, N0, rp0, csr0, dv0, W1, b1, Bb, A);

    // pool 0 -> 1
    k_interp<<<cdiv(N1 * 32, 256), 256, 0, stream>>>((const float4*)A, kidx1, kw1, (float4*)Bb, N1);

    // level 1 conv
    conv128(Bb, pos1, N1, rp1, csr1, dv1, W2, b2, A, Bb);

    // pool 1 -> 2
    k_interp<<<cdiv(N2 * 32, 256), 256, 0, stream>>>((const float4*)Bb, kidx2, kw2, (float4*)A, N2);

    // level 2 conv
    conv128(A, pos2, N2, rp2, csr2, dv2, W3, b3, Bb, A);

    // output conv (OC=5)
    k_matmul5<<<cdiv(N2, 32), 256, 0, stream>>>(A, pos2, W4, dv2, xw5, N2);
    k_gather5<<<cdiv(N2 * 8, 256), 256, 0, stream>>>(rp2, csr2, xw5, dv2, b4, out, N2);
}

// Round 16
// 873.099 us; speedup vs baseline: 1.1803x; 1.0608x over previous
//
#include <hip/hip_runtime.h>
#include <math.h>

#define TAN30f 0.57735026918962576f
#define SELU_SCALE 1.0507009873554805f
#define SELU_ALPHA 1.6732632423543772f

#define MAXC 65536   // max grid cells
#define MAXG 40
#define BBOXBLK 64
#define PPC_T 0.4f   // target ~2.5 pts/cell (was 0.2 -> ~5/cell); r=1 ball still holds ~10 pts

__device__ __forceinline__ float selu_f(float x) {
    return SELU_SCALE * (x > 0.0f ? x : SELU_ALPHA * expm1f(x));
}

struct GP {
    float ox, oy, oz, ihx, ihy, ihz, hmin2, pad;
    int Gx, Gy, Gz, maxG;
};

// ---------- dense matmul: Y[N,128] = concat(X[N,FIC], P[N,3]?) @ W ----------
template<int FIC, bool HAS_POS, bool BIAS_SELU, bool ROWSCALE>
__global__ __launch_bounds__(256) void k_matmul128(
    const float* __restrict__ X, const float* __restrict__ P,
    const float* __restrict__ W, const float* __restrict__ bias,
    const float* __restrict__ rs,
    float* __restrict__ Y, int N)
{
    constexpr int ICT = FIC + (HAS_POS ? 3 : 0);
    __shared__ float xs[16][ICT + 1];
    int row0 = blockIdx.x * 16;

    for (int idx = threadIdx.x; idx < 16 * FIC; idx += 256) {
        int r = idx / FIC, c = idx % FIC;
        int gr = row0 + r;
        xs[r][c] = (gr < N) ? X[gr * FIC + c] : 0.0f;
    }
    if (HAS_POS) {
        for (int idx = threadIdx.x; idx < 16 * 3; idx += 256) {
            int r = idx / 3, c = idx % 3;
            int gr = row0 + r;
            xs[r][FIC + c] = (gr < N) ? P[gr * 3 + c] : 0.0f;
        }
    }
    __syncthreads();

    int col = threadIdx.x & 127;
    int half = threadIdx.x >> 7;
    float acc[8];
#pragma unroll
    for (int r = 0; r < 8; ++r) acc[r] = 0.0f;

#pragma unroll 4
    for (int i = 0; i < ICT; ++i) {
        float wv = W[i * 128 + col];
#pragma unroll
        for (int r = 0; r < 8; ++r)
            acc[r] = fmaf(xs[half * 8 + r][i], wv, acc[r]);
    }

    float bv = BIAS_SELU ? bias[col] : 0.0f;
#pragma unroll
    for (int r = 0; r < 8; ++r) {
        int gr = row0 + half * 8 + r;
        if (gr < N) {
            float v = acc[r];
            if (BIAS_SELU) v = selu_f(v + bv);
            if (ROWSCALE) v *= rs[gr];
            Y[gr * 128 + col] = v;
        }
    }
}

// ---------- batched triple graph build (all levels at once) ----------
__global__ void k_hist3(const int* __restrict__ c0, int E0, int* __restrict__ n0,
                        const int* __restrict__ c1, int E1, int* __restrict__ n1,
                        const int* __restrict__ c2, int E2, int* __restrict__ n2) {
    int i = blockIdx.x * 256 + threadIdx.x;
    if (i < E0) atomicAdd(&n0[c0[i]], 1);
    else if (i < E0 + E1) atomicAdd(&n1[c1[i - E0]], 1);
    else if (i < E0 + E1 + E2) atomicAdd(&n2[c2[i - E0 - E1]], 1);
}

__global__ __launch_bounds__(256) void k_scan1t(
    const int* __restrict__ in0, int* __restrict__ out0, float* __restrict__ dva, int n0a,
    const int* __restrict__ in1, int* __restrict__ out1, float* __restrict__ dvb, int n1a,
    const int* __restrict__ in2, int* __restrict__ out2, float* __restrict__ dvc, int n2a,
    int* __restrict__ bsum, int nbmax)
{
    int y = blockIdx.y;
    const int* in = y == 0 ? in0 : (y == 1 ? in1 : in2);
    int* out = y == 0 ? out0 : (y == 1 ? out1 : out2);
    float* dv = y == 0 ? dva : (y == 1 ? dvb : dvc);
    int n = y == 0 ? n0a : (y == 1 ? n1a : n2a);
    __shared__ int s[256];
    int tid = threadIdx.x;
    int base = blockIdx.x * 1024 + tid * 4;
    int a[4];
#pragma unroll
    for (int k = 0; k < 4; ++k) a[k] = (base + k < n) ? in[base + k] : 0;
#pragma unroll
    for (int k = 0; k < 4; ++k)
        if (base + k < n) dv[base + k] = rsqrtf((float)a[k] + 1.0f);
    int t = a[0] + a[1] + a[2] + a[3];
    s[tid] = t;
    __syncthreads();
    for (int off = 1; off < 256; off <<= 1) {
        int x = (tid >= off) ? s[tid - off] : 0;
        __syncthreads();
        s[tid] += x;
        __syncthreads();
    }
    int run = s[tid] - t;
#pragma unroll
    for (int k = 0; k < 4; ++k) {
        if (base + k < n) out[base + k] = run;
        run += a[k];
    }
    if (tid == 255) bsum[y * nbmax + blockIdx.x] = s[255];
}

__global__ void k_scan2(int* __restrict__ bsum, int nb) {
    if (threadIdx.x == 0) {
        int* b = bsum + blockIdx.x * nb;
        int run = 0;
        for (int i = 0; i < nb; ++i) { int v = b[i]; b[i] = run; run += v; }
    }
}

__global__ void k_scan3t(int* __restrict__ rp0, int* __restrict__ cu0, int E0, int n0a,
                         int* __restrict__ rp1, int* __restrict__ cu1, int E1, int n1a,
                         int* __restrict__ rp2, int* __restrict__ cu2, int E2, int n2a,
                         const int* __restrict__ bsum, int nbmax) {
    int y = blockIdx.y;
    int* rp = y == 0 ? rp0 : (y == 1 ? rp1 : rp2);
    int* cu = y == 0 ? cu0 : (y == 1 ? cu1 : cu2);
    int E = y == 0 ? E0 : (y == 1 ? E1 : E2);
    int n = y == 0 ? n0a : (y == 1 ? n1a : n2a);
    const int* bs = bsum + y * nbmax;
    int i = blockIdx.x * 256 + threadIdx.x;
    if (i < n) {
        int v = rp[i] + bs[i >> 10];
        rp[i] = v;
        cu[i] = v;
    }
    if (i == 0) rp[n] = E;
}

__global__ void k_scatter3(const int* __restrict__ ei0, int E0, int* __restrict__ cu0, int* __restrict__ cs0,
                           const int* __restrict__ ei1, int E1, int* __restrict__ cu1, int* __restrict__ cs1,
                           const int* __restrict__ ei2, int E2, int* __restrict__ cu2, int* __restrict__ cs2) {
    int i = blockIdx.x * 256 + threadIdx.x;
    const int* ei; int E; int* cur; int* csr; int e;
    if (i < E0)               { ei = ei0; E = E0; cur = cu0; csr = cs0; e = i; }
    else if (i < E0 + E1)     { ei = ei1; E = E1; cur = cu1; csr = cs1; e = i - E0; }
    else if (i < E0 + E1 + E2){ ei = ei2; E = E2; cur = cu2; csr = cs2; e = i - E0 - E1; }
    else return;
    int r = ei[e], c = ei[E + e];
    int p = atomicAdd(&cur[c], 1);
    csr[p] = r;
}

// ---------- CSR gather aggregation, float4-vectorized (32 thr/node) ----------
__global__ __launch_bounds__(256) void k_gather128(
    const int* __restrict__ rowptr, const int* __restrict__ csr,
    const float4* __restrict__ xws4, const float* __restrict__ dv,
    const float4* __restrict__ bias4, float4* __restrict__ out4, int N)
{
    int t = blockIdx.x * 256 + threadIdx.x;
    int node = t >> 5, c4 = t & 31;
    if (node >= N) return;
    int s = rowptr[node], e = rowptr[node + 1];
    float4 acc = xws4[(size_t)node * 32 + c4];  // self loop (already *dinv[node])
    for (int i = s; i < e; ++i) {
        int src = csr[i];
        float4 v = xws4[(size_t)src * 32 + c4];
        acc.x += v.x; acc.y += v.y; acc.z += v.z; acc.w += v.w;
    }
    float d = dv[node];
    float4 b = bias4[c4];
    float4 o;
    o.x = selu_f(fmaf(acc.x, d, b.x));
    o.y = selu_f(fmaf(acc.y, d, b.y));
    o.z = selu_f(fmaf(acc.z, d, b.z));
    o.w = selu_f(fmaf(acc.w, d, b.w));
    out4[(size_t)node * 32 + c4] = o;
}

__global__ __launch_bounds__(256) void k_gather5(
    const int* __restrict__ rowptr, const int* __restrict__ csr,
    const float* __restrict__ xws, const float* __restrict__ dv,
    const float* __restrict__ bias, float* __restrict__ out, int N)
{
    int t = blockIdx.x * 256 + threadIdx.x;
    int node = t >> 3, ch = t & 7;
    if (node >= N || ch >= 5) return;
    int s = rowptr[node], e = rowptr[node + 1];
    float acc = xws[(size_t)node * 5 + ch];
    for (int i = s; i < e; ++i) {
        int src = csr[i];
        acc += xws[(size_t)src * 5 + ch];
    }
    out[(size_t)node * 5 + ch] = acc * dv[node] + bias[ch];
}

// ---------- onera transform (all 3 levels fused); emits {x,y,z,|p|^2} ----------
__global__ void k_transform3(const float* __restrict__ p0, float4* __restrict__ t0, int n0,
                             const float* __restrict__ p1, float4* __restrict__ t1, int n1,
                             const float* __restrict__ p2, float4* __restrict__ t2, int n2) {
    int i = blockIdx.x * 256 + threadIdx.x;
    const float* pos; float4* tp; int li;
    if (i < n0) { pos = p0; tp = t0; li = i; }
    else if (i < n0 + n1) { pos = p1; tp = t1; li = i - n0; }
    else if (i < n0 + n1 + n2) { pos = p2; tp = t2; li = i - n0 - n1; }
    else return;
    float x = pos[li * 3 + 0], y = pos[li * 3 + 1], z = pos[li * 3 + 2];
    float nx = x - TAN30f * y;
    float f = 1.0f + (1.0f / 0.56f - 1.0f) * (y / 1.1963f);
    float X = nx * f, Y = y * f, Z = z * f;
    tp[li] = make_float4(X, Y, Z, (X * X + Y * Y) + Z * Z);
}

// ---------- spatial grid kNN (both levels fused) ----------
__global__ __launch_bounds__(256) void k_bbox2(const float4* __restrict__ tpa, int na,
                                               const float4* __restrict__ tpb, int nb,
                                               float* __restrict__ bbp) {
    const float4* tp = blockIdx.y ? tpb : tpa;
    int n = blockIdx.y ? nb : na;
    __shared__ float red[6][256];
    float mn0 = 3.4e38f, mn1 = 3.4e38f, mn2 = 3.4e38f;
    float mx0 = -3.4e38f, mx1 = -3.4e38f, mx2 = -3.4e38f;
    for (int i = blockIdx.x * 256 + threadIdx.x; i < n; i += gridDim.x * 256) {
        float4 t = tp[i];
        mn0 = fminf(mn0, t.x); mx0 = fmaxf(mx0, t.x);
        mn1 = fminf(mn1, t.y); mx1 = fmaxf(mx1, t.y);
        mn2 = fminf(mn2, t.z); mx2 = fmaxf(mx2, t.z);
    }
    int tid = threadIdx.x;
    red[0][tid] = mn0; red[1][tid] = mn1; red[2][tid] = mn2;
    red[3][tid] = mx0; red[4][tid] = mx1; red[5][tid] = mx2;
    __syncthreads();
    for (int off = 128; off > 0; off >>= 1) {
        if (tid < off) {
#pragma unroll
            for (int k = 0; k < 3; ++k) {
                red[k][tid] = fminf(red[k][tid], red[k][tid + off]);
                red[3 + k][tid] = fmaxf(red[3 + k][tid], red[3 + k][tid + off]);
            }
        }
        __syncthreads();
    }
    if (tid == 0) {
        float* o = bbp + (blockIdx.y * BBOXBLK + blockIdx.x) * 6;
#pragma unroll
        for (int k = 0; k < 3; ++k) {
            o[k] = red[k][0];
            o[3 + k] = red[3 + k][0];
        }
    }
}

__global__ void k_gridparams2(const float* __restrict__ bbp, int na, int nb,
                              GP* __restrict__ gps) {
    if (threadIdx.x != 0) return;
    int set = blockIdx.x;
    const float* bp = bbp + set * BBOXBLK * 6;
    int n = set ? nb : na;
    GP* gp = gps + set;
    float mn[3] = {3.4e38f, 3.4e38f, 3.4e38f};
    float mx[3] = {-3.4e38f, -3.4e38f, -3.4e38f};
    for (int i = 0; i < BBOXBLK; ++i) {
#pragma unroll
        for (int k = 0; k < 3; ++k) {
            mn[k] = fminf(mn[k], bp[i * 6 + k]);
            mx[k] = fmaxf(mx[k], bp[i * 6 + 3 + k]);
        }
    }
    float e[3], o[3];
#pragma unroll
    for (int k = 0; k < 3; ++k) {
        float ext = fmaxf(mx[k] - mn[k], 1e-6f);
        float padv = ext * 1e-4f + 1e-6f;
        o[k] = mn[k] - padv;
        e[k] = ext + 2.0f * padv;
    }
    float T = (float)n * PPC_T;
    float s = cbrtf(T / (e[0] * e[1] * e[2]));
    int G[3];
#pragma unroll
    for (int k = 0; k < 3; ++k) {
        int g = (int)ceilf(e[k] * s);
        G[k] = g < 1 ? 1 : (g > MAXG ? MAXG : g);
    }
    float h[3];
#pragma unroll
    for (int k = 0; k < 3; ++k) h[k] = e[k] / (float)G[k];
    float hmin = fminf(h[0], fminf(h[1], h[2]));
    gp->ox = o[0]; gp->oy = o[1]; gp->oz = o[2];
    gp->ihx = (float)G[0] / e[0]; gp->ihy = (float)G[1] / e[1]; gp->ihz = (float)G[2] / e[2];
    gp->hmin2 = hmin * hmin;
    gp->Gx = G[0]; gp->Gy = G[1]; gp->Gz = G[2];
    gp->maxG = max(G[0], max(G[1], G[2]));
}

__device__ __forceinline__ int cell_of(float4 t, const GP* gp) {
    int cx = min(max((int)((t.x - gp->ox) * gp->ihx), 0), gp->Gx - 1);
    int cy = min(max((int)((t.y - gp->oy) * gp->ihy), 0), gp->Gy - 1);
    int cz = min(max((int)((t.z - gp->oz) * gp->ihz), 0), gp->Gz - 1);
    return (cz * gp->Gy + cy) * gp->Gx + cx;
}

// 4 segments: ref0 (tp0,gp0) | q1 (tp1,gp0) | ref1 (tp1,gp1) | q2 (tp2,gp1)
__global__ void k_cellid4(const float4* __restrict__ tp0, int N0,
                          const float4* __restrict__ tp1, int N1,
                          const float4* __restrict__ tp2, int N2,
                          int* __restrict__ gcell0, int* __restrict__ qcell1,
                          int* __restrict__ gcell1, int* __restrict__ qcell2,
                          int* __restrict__ cnt, const GP* __restrict__ gps) {
    int i = blockIdx.x * 256 + threadIdx.x;
    const float4* tp; const GP* gp; int* cellout; int* cn; int li;
    if (i < N0)                { tp = tp0; gp = gps;     cellout = gcell0; cn = cnt;            li = i; }
    else if (i < N0 + N1)      { tp = tp1; gp = gps;     cellout = qcell1; cn = cnt + MAXC;     li = i - N0; }
    else if (i < N0 + 2 * N1)  { tp = tp1; gp = gps + 1; cellout = gcell1; cn = cnt + 2 * MAXC; li = i - N0 - N1; }
    else if (i < N0 + 2 * N1 + N2) { tp = tp2; gp = gps + 1; cellout = qcell2; cn = cnt + 3 * MAXC; li = i - N0 - 2 * N1; }
    else return;
    int cid = cell_of(tp[li], gp);
    cellout[li] = cid;
    atomicAdd(&cn[cid], 1);
}

__global__ __launch_bounds__(256) void k_scan1c(const int* __restrict__ cnt,
                                                int* __restrict__ row,
                                                int* __restrict__ bsum, int nb) {
    const int* in = cnt + blockIdx.y * MAXC;
    int* out = row + blockIdx.y * (MAXC + 1);
    __shared__ int s[256];
    int tid = threadIdx.x;
    int base = blockIdx.x * 1024 + tid * 4;
    int a[4];
#pragma unroll
    for (int k = 0; k < 4; ++k) a[k] = (base + k < MAXC) ? in[base + k] : 0;
    int t = a[0] + a[1] + a[2] + a[3];
    s[tid] = t;
    __syncthreads();
    for (int off = 1; off < 256; off <<= 1) {
        int x = (tid >= off) ? s[tid - off] : 0;
        __syncthreads();
        s[tid] += x;
        __syncthreads();
    }
    int run = s[tid] - t;
#pragma unroll
    for (int k = 0; k < 4; ++k) {
        if (base + k < MAXC) out[base + k] = run;
        run += a[k];
    }
    if (tid == 255) bsum[blockIdx.y * nb + blockIdx.x] = s[255];
}

__global__ void k_scan3c(int* __restrict__ row, int* __restrict__ cur,
                         const int* __restrict__ bsum, int nb, int4 E4) {
    int y = blockIdx.y;
    int* rp = row + y * (MAXC + 1);
    int* cu = cur + y * MAXC;
    const int* bs = bsum + y * nb;
    int E = (y == 0) ? E4.x : (y == 1) ? E4.y : (y == 2) ? E4.z : E4.w;
    int i = blockIdx.x * 256 + threadIdx.x;
    if (i < MAXC) {
        int v = rp[i] + bs[i >> 10];
        rp[i] = v;
        cu[i] = v;
    }
    if (i == 0) rp[MAXC] = E;
}

__global__ void k_scatter4(const float4* __restrict__ tp0, int N0,
                           const float4* __restrict__ tp1, int N1,
                           const float4* __restrict__ tp2, int N2,
                           const int* __restrict__ gcell0, const int* __restrict__ qcell1,
                           const int* __restrict__ gcell1, const int* __restrict__ qcell2,
                           int* __restrict__ cur,
                           float4* __restrict__ gpts0, float4* __restrict__ gpts1,
                           int* __restrict__ qorder1, int* __restrict__ qorder2) {
    int i = blockIdx.x * 256 + threadIdx.x;
    if (i < N0) {
        int p = atomicAdd(&cur[gcell0[i]], 1);
        float4 t = tp0[i];
        t.w = __int_as_float(i);
        gpts0[p] = t;
    } else if (i < N0 + N1) {
        int j = i - N0;
        int p = atomicAdd(&cur[MAXC + qcell1[j]], 1);
        qorder1[p] = j;
    } else if (i < N0 + 2 * N1) {
        int j = i - N0 - N1;
        int p = atomicAdd(&cur[2 * MAXC + gcell1[j]], 1);
        float4 t = tp1[j];
        t.w = __int_as_float(j);
        gpts1[p] = t;
    } else if (i < N0 + 2 * N1 + N2) {
        int j = i - N0 - 2 * N1;
        int p = atomicAdd(&cur[3 * MAXC + qcell2[j]], 1);
        qorder2[p] = j;
    }
}

// Both levels' searches in one launch; point scan unrolled x4 (proven
// R13 config — x8 spills to scratch, WRITE_SIZE 10->32 MB, regressed).
__global__ __launch_bounds__(256) void k_knn_grid2(
    const float4* __restrict__ tpq1, int N1, const int* __restrict__ qorder1,
    const float4* __restrict__ gpts0, const int* __restrict__ crow0,
    int* __restrict__ oidx1, float* __restrict__ ow1,
    const float4* __restrict__ tpq2, int N2, const int* __restrict__ qorder2,
    const float4* __restrict__ gpts1, const int* __restrict__ crow1,
    int* __restrict__ oidx2, float* __restrict__ ow2,
    const GP* __restrict__ gps)
{
    int t = blockIdx.x * 256 + threadIdx.x;
    const float4* tpq; const int* qord; const float4* gpts; const int* crow;
    const GP* gp; int* oidx; float* ow; int slot; int Nq;
    if (t < N1) {
        tpq = tpq1; qord = qorder1; gpts = gpts0; crow = crow0;
        gp = gps; oidx = oidx1; ow = ow1; slot = t; Nq = N1;
    } else {
        tpq = tpq2; qord = qorder2; gpts = gpts1; crow = crow1;
        gp = gps + 1; oidx = oidx2; ow = ow2; slot = t - N1; Nq = N2;
    }
    bool active = slot < Nq;
    int qi = active ? qord[slot] : 0;

    float ox = gp->ox, oy = gp->oy, oz = gp->oz;
    float ihx = gp->ihx, ihy = gp->ihy, ihz = gp->ihz;
    float hmin2 = gp->hmin2;
    int Gx = gp->Gx, Gy = gp->Gy, Gz = gp->Gz, maxG = gp->maxG;

    float qx = 0, qy = 0, qz = 0, q2 = 0;
    if (active) { float4 tq = tpq[qi]; qx = tq.x; qy = tq.y; qz = tq.z; q2 = tq.w; }
    int cx = min(max((int)((qx - ox) * ihx), 0), Gx - 1);
    int cy = min(max((int)((qy - oy) * ihy), 0), Gy - 1);
    int cz = min(max((int)((qz - oz) * ihz), 0), Gz - 1);

    float d0 = 3.4e38f, d1 = 3.4e38f, d2 = 3.4e38f;
    int j0 = 0x7FFFFFFF, j1 = 0x7FFFFFFF, j2 = 0x7FFFFFFF;

    auto insert = [&](float d, int id) {
        // lexicographic (d, id) — matches top_k tie order
        if (d < d2 || (d == d2 && id < j2)) {
            if (d < d1 || (d == d1 && id < j1)) {
                d2 = d1; j2 = j1;
                if (d < d0 || (d == d0 && id < j0)) {
                    d1 = d0; j1 = j0; d0 = d; j0 = id;
                } else { d1 = d; j1 = id; }
            } else { d2 = d; j2 = id; }
        }
    };
    auto proc = [&](float4 p) {
        int id = __float_as_int(p.w);
        float px2 = fmaf(p.z, p.z, fmaf(p.y, p.y, p.x * p.x));
        float dot = fmaf(p.z, qz, fmaf(p.y, qy, p.x * qx));
        float d = (q2 - 2.0f * dot) + px2;
        insert(d, id);
    };
    auto scan_range = [&](int s, int e) {
        int i = s;
        for (; i + 3 < e; i += 4) {
            float4 pa = gpts[i], pb = gpts[i + 1], pc = gpts[i + 2], pd = gpts[i + 3];
            proc(pa); proc(pb); proc(pc); proc(pd);
        }
        for (; i < e; ++i) { float4 p = gpts[i]; proc(p); }
    };
    auto scan_cells = [&](int zz, int yy, int xlo, int xhi) {
        int base = (zz * Gy + yy) * Gx;
        scan_range(crow[base + xlo], crow[base + xhi + 1]);
    };

    {
        int xlo = max(cx - 1, 0), xhi = min(cx + 1, Gx - 1);
        int rs[9], re[9];
#pragma unroll
        for (int k = 0; k < 9; ++k) {
            int zz = cz + k / 3 - 1, yy = cy + k % 3 - 1;
            bool ok = active && zz >= 0 && zz < Gz && yy >= 0 && yy < Gy;
            int base = ok ? (zz * Gy + yy) * Gx : 0;
            int a = crow[base + (ok ? xlo : 0)];
            int b = crow[base + (ok ? xhi + 1 : 0)];
            rs[k] = ok ? a : 0;
            re[k] = ok ? b : 0;
        }
#pragma unroll
        for (int k = 0; k < 9; ++k) scan_range(rs[k], re[k]);
    }
    bool done = !active || (d2 < hmin2);   // guarantee radius 1*hmin after r=1 cube

    for (int r = 2; r <= maxG; ++r) {
        if (__all(done)) break;
        if (!done) {
            int xlo = max(cx - r, 0), xhi = min(cx + r, Gx - 1);
            for (int zz = max(cz - r, 0); zz <= min(cz + r, Gz - 1); ++zz)
                for (int yy = max(cy - r, 0); yy <= min(cy + r, Gy - 1); ++yy) {
                    if (max(abs(zz - cz), abs(yy - cy)) == r) {
                        scan_cells(zz, yy, xlo, xhi);        // full edge row
                    } else {
                        if (cx - r >= 0)      scan_cells(zz, yy, cx - r, cx - r);
                        if (cx + r <= Gx - 1) scan_cells(zz, yy, cx + r, cx + r);
                    }
                }
            done = d2 < hmin2 * (float)(r * r);
        }
    }

    if (active) {
        float w0 = 1.0f / fmaxf(d0, 1e-16f);
        float w1 = 1.0f / fmaxf(d1, 1e-16f);
        float w2 = 1.0f / fmaxf(d2, 1e-16f);
        float s = w0 + w1 + w2;
        oidx[qi * 3 + 0] = j0; oidx[qi * 3 + 1] = j1; oidx[qi * 3 + 2] = j2;
        ow[qi * 4 + 0] = w0; ow[qi * 4 + 1] = w1; ow[qi * 4 + 2] = w2; ow[qi * 4 + 3] = s;
    }
}

// ---------- knn interpolate, float4-vectorized (32 thr/query) ----------
__global__ void k_interp(const float4* __restrict__ x4, const int* __restrict__ idx,
                         const float* __restrict__ w, float4* __restrict__ y4, int Nq) {
    int t = blockIdx.x * 256 + threadIdx.x;
    if (t >= Nq * 32) return;
    int j = t >> 5, c = t & 31;
    int i0 = idx[j * 3], i1 = idx[j * 3 + 1], i2 = idx[j * 3 + 2];
    float w0 = w[j * 4], w1 = w[j * 4 + 1], w2 = w[j * 4 + 2], s = w[j * 4 + 3];
    float inv = 1.0f / s;
    float4 a = x4[(size_t)i0 * 32 + c];
    float4 b = x4[(size_t)i1 * 32 + c];
    float4 d = x4[(size_t)i2 * 32 + c];
    float4 o;
    o.x = (w0 * a.x + w1 * b.x + w2 * d.x) * inv;
    o.y = (w0 * a.y + w1 * b.y + w2 * d.y) * inv;
    o.z = (w0 * a.z + w1 * b.z + w2 * d.z) * inv;
    o.w = (w0 * a.w + w1 * b.w + w2 * d.w) * inv;
    y4[(size_t)j * 32 + c] = o;
}

// ---------- output conv matmul (OC=5), row-scaled by dinv ----------
__global__ __launch_bounds__(256) void k_matmul5(const float* __restrict__ X, const float* __restrict__ P,
                                                 const float* __restrict__ W, const float* __restrict__ rs,
                                                 float* __restrict__ Y, int N) {
    __shared__ float xs[32][132];
    __shared__ float ws[131 * 5];
    int row0 = blockIdx.x * 32;
    for (int idx = threadIdx.x; idx < 131 * 5; idx += 256) ws[idx] = W[idx];
    for (int idx = threadIdx.x; idx < 32 * 128; idx += 256) {
        int r = idx >> 7, c = idx & 127;
        xs[r][c] = X[(size_t)(row0 + r) * 128 + c];
    }
    for (int idx = threadIdx.x; idx < 32 * 3; idx += 256) {
        int r = idx / 3, c = idx % 3;
        xs[r][128 + c] = P[(row0 + r) * 3 + c];
    }
    __syncthreads();
    int r = threadIdx.x >> 3;
    int c = threadIdx.x & 7;
    if (c < 5) {
        float acc = 0.0f;
        for (int i = 0; i < 131; ++i) acc = fmaf(xs[r][i], ws[i * 5 + c], acc);
        Y[(size_t)(row0 + r) * 5 + c] = acc * rs[row0 + r];
    }
}

extern "C" void kernel_launch(void* const* d_in, const int* in_sizes, int n_in,
                              void* d_out, int out_size, void* d_ws, size_t ws_size,
                              hipStream_t stream) {
    const float* latent = (const float*)d_in[0];
    const float* pos0   = (const float*)d_in[1];
    const float* pos1   = (const float*)d_in[2];
    const float* pos2   = (const float*)d_in[3];
    const float* W_lin  = (const float*)d_in[4];
    const float* b_lin  = (const float*)d_in[5];
    const float* W0 = (const float*)d_in[6];  const float* b0 = (const float*)d_in[7];
    const float* W1 = (const float*)d_in[8];  const float* b1 = (const float*)d_in[9];
    const float* W2 = (const float*)d_in[10]; const float* b2 = (const float*)d_in[11];
    const float* W3 = (const float*)d_in[12]; const float* b3 = (const float*)d_in[13];
    const float* W4 = (const float*)d_in[14]; const float* b4 = (const float*)d_in[15];
    const int* ei0 = (const int*)d_in[16];
    const int* ei1 = (const int*)d_in[17];
    const int* ei2 = (const int*)d_in[18];
    float* out = (float*)d_out;

    const int N0 = in_sizes[1] / 3, N1 = in_sizes[2] / 3, N2 = in_sizes[3] / 3;
    const int E0 = in_sizes[16] / 2, E1 = in_sizes[17] / 2, E2 = in_sizes[18] / 2;

    char* wsp = (char*)d_ws;
    auto alloc = [&](size_t bytes) {
        char* p = wsp;
        wsp += (bytes + 255) & ~size_t(255);
        return p;
    };
    float*    A       = (float*)alloc((size_t)N2 * 128 * 4);
    float*    Bb      = (float*)alloc((size_t)N2 * 128 * 4);
    float4*   tp0     = (float4*)alloc((size_t)N0 * 16);
    float4*   tp1     = (float4*)alloc((size_t)N1 * 16);
    float4*   tp2     = (float4*)alloc((size_t)N2 * 16);
    // per-level graph structures (built once, persist)
    float*    dv0     = (float*)alloc((size_t)N0 * 4);
    float*    dv1     = (float*)alloc((size_t)N1 * 4);
    float*    dv2     = (float*)alloc((size_t)N2 * 4);
    int*      cnt012  = (int*)  alloc((size_t)(N0 + N1 + N2) * 4);
    int*      cnt0 = cnt012, *cnt1 = cnt012 + N0, *cnt2 = cnt012 + N0 + N1;
    int*      rp0     = (int*)  alloc(((size_t)N0 + 1) * 4);
    int*      rp1     = (int*)  alloc(((size_t)N1 + 1) * 4);
    int*      rp2     = (int*)  alloc(((size_t)N2 + 1) * 4);
    int*      cur0    = (int*)  alloc((size_t)N0 * 4);
    int*      cur1    = (int*)  alloc((size_t)N1 * 4);
    int*      cur2    = (int*)  alloc((size_t)N2 * 4);
    int*      csr0    = (int*)  alloc((size_t)E0 * 4);
    int*      csr1    = (int*)  alloc((size_t)E1 * 4);
    int*      csr2    = (int*)  alloc((size_t)E2 * 4);
    int*      bsum    = (int*)  alloc(4096);
    float*    xw5     = (float*)alloc((size_t)N2 * 5 * 4);
    float*    bbp     = (float*)alloc((size_t)2 * BBOXBLK * 6 * 4);
    GP*       gps     = (GP*)   alloc(2 * sizeof(GP));
    int*      knncnt  = (int*)  alloc((size_t)4 * MAXC * 4);
    int*      knnrow  = (int*)  alloc((size_t)4 * (MAXC + 1) * 4);
    int*      knncur  = (int*)  alloc((size_t)4 * MAXC * 4);
    int*      gcell0  = (int*)  alloc((size_t)N0 * 4);
    int*      gcell1  = (int*)  alloc((size_t)N1 * 4);
    int*      qcell1  = (int*)  alloc((size_t)N1 * 4);
    int*      qcell2  = (int*)  alloc((size_t)N2 * 4);
    float4*   gpts0   = (float4*)alloc((size_t)N0 * 16);
    float4*   gpts1   = (float4*)alloc((size_t)N1 * 16);
    int*      qorder1 = (int*)  alloc((size_t)N1 * 4);
    int*      qorder2 = (int*)  alloc((size_t)N2 * 4);
    int*      kidx1   = (int*)  alloc((size_t)N1 * 3 * 4);
    float*    kw1     = (float*)alloc((size_t)N1 * 4 * 4);
    int*      kidx2   = (int*)  alloc((size_t)N2 * 3 * 4);
    float*    kw2     = (float*)alloc((size_t)N2 * 4 * 4);

    auto cdiv = [](int a, int b) { return (a + b - 1) / b; };

    // transforms (one launch)
    k_transform3<<<cdiv(N0 + N1 + N2, 256), 256, 0, stream>>>(pos0, tp0, N0, pos1, tp1, N1,
                                                              pos2, tp2, N2);

    // ---- both kNN levels fused ----
    {
        k_bbox2<<<dim3(BBOXBLK, 2), 256, 0, stream>>>(tp0, N0, tp1, N1, bbp);
        k_gridparams2<<<2, 64, 0, stream>>>(bbp, N0, N1, gps);
        hipMemsetAsync(knncnt, 0, (size_t)4 * MAXC * 4, stream);
        int tot = N0 + 2 * N1 + N2;
        k_cellid4<<<cdiv(tot, 256), 256, 0, stream>>>(tp0, N0, tp1, N1, tp2, N2,
                                                      gcell0, qcell1, gcell1, qcell2,
                                                      knncnt, gps);
        int nbc = cdiv(MAXC, 1024);
        k_scan1c<<<dim3(nbc, 4), 256, 0, stream>>>(knncnt, knnrow, bsum, nbc);
        k_scan2<<<4, 64, 0, stream>>>(bsum, nbc);
        k_scan3c<<<dim3(cdiv(MAXC, 256), 4), 256, 0, stream>>>(knnrow, knncur, bsum, nbc,
                                                               make_int4(N0, N1, N1, N2));
        k_scatter4<<<cdiv(tot, 256), 256, 0, stream>>>(tp0, N0, tp1, N1, tp2, N2,
                                                       gcell0, qcell1, gcell1, qcell2,
                                                       knncur, gpts0, gpts1, qorder1, qorder2);
        k_knn_grid2<<<cdiv(N1 + N2, 256), 256, 0, stream>>>(
            tp1, N1, qorder1, gpts0, knnrow, kidx1, kw1,
            tp2, N2, qorder2, gpts1, knnrow + 2 * (MAXC + 1), kidx2, kw2, gps);
    }

    // ---- all three graph builds batched ----
    {
        hipMemsetAsync(cnt012, 0, (size_t)(N0 + N1 + N2) * 4, stream);
        k_hist3<<<cdiv(E0 + E1 + E2, 256), 256, 0, stream>>>(ei0 + E0, E0, cnt0,
                                                             ei1 + E1, E1, cnt1,
                                                             ei2 + E2, E2, cnt2);
        int nbmax = cdiv(N2, 1024);
        k_scan1t<<<dim3(nbmax, 3), 256, 0, stream>>>(cnt0, rp0, dv0, N0,
                                                     cnt1, rp1, dv1, N1,
                                                     cnt2, rp2, dv2, N2, bsum, nbmax);
        k_scan2<<<3, 64, 0, stream>>>(bsum, nbmax);
        k_scan3t<<<dim3(cdiv(N2, 256), 3), 256, 0, stream>>>(rp0, cur0, E0, N0,
                                                             rp1, cur1, E1, N1,
                                                             rp2, cur2, E2, N2, bsum, nbmax);
        k_scatter3<<<cdiv(E0 + E1 + E2, 256), 256, 0, stream>>>(ei0, E0, cur0, csr0,
                                                                ei1, E1, cur1, csr1,
                                                                ei2, E2, cur2, csr2);
    }

    auto conv128 = [&](const float* x, const float* pos, int N,
                       const int* rp, const int* csr, const float* dv,
                       const float* W, const float* b, float* xws, float* outb) {
        k_matmul128<128, true, false, true><<<cdiv(N, 16), 256, 0, stream>>>(x, pos, W, nullptr, dv, xws, N);
        k_gather128<<<cdiv(N * 32, 256), 256, 0, stream>>>(rp, csr, (const float4*)xws, dv,
                                                           (const float4*)b, (float4*)outb, N);
    };

    // x = selu(latent @ W_lin + b_lin)  -> A
    k_matmul128<64, false, true, false><<<cdiv(N0, 16), 256, 0, stream>>>(latent, nullptr, W_lin, b_lin, nullptr, A, N0);

    // level 0: two convs
    conv128(A, pos0, N0, rp0, csr0, dv0, W0, b0, Bb, A);
    conv128(A, pos0, N0, rp0, csr0, dv0, W1, b1, Bb, A);

    // pool 0 -> 1
    k_interp<<<cdiv(N1 * 32, 256), 256, 0, stream>>>((const float4*)A, kidx1, kw1, (float4*)Bb, N1);

    // level 1 conv
    conv128(Bb, pos1, N1, rp1, csr1, dv1, W2, b2, A, Bb);

    // pool 1 -> 2
    k_interp<<<cdiv(N2 * 32, 256), 256, 0, stream>>>((const float4*)Bb, kidx2, kw2, (float4*)A, N2);

    // level 2 conv
    conv128(A, pos2, N2, rp2, csr2, dv2, W3, b3, Bb, A);

    // output conv (OC=5)
    k_matmul5<<<cdiv(N2, 32), 256, 0, stream>>>(A, pos2, W4, dv2, xw5, N2);
    k_gather5<<<cdiv(N2 * 8, 256), 256, 0, stream>>>(rp2, csr2, xw5, dv2, b4, out, N2);
}

// Round 17
// 831.517 us; speedup vs baseline: 1.2393x; 1.0500x over previous
//
#include <hip/hip_runtime.h>
#include <math.h>

#define TAN30f 0.57735026918962576f
#define SELU_SCALE 1.0507009873554805f
#define SELU_ALPHA 1.6732632423543772f

#define MAXC 65536   // max grid cells
#define MAXG 40
#define BBOXBLK 64
#define PPC_T 0.8f   // target ~1.25 pts/cell; r=1 ball holds ~5.2 expected (>3), ~11% ring rate

__device__ __forceinline__ float selu_f(float x) {
    return SELU_SCALE * (x > 0.0f ? x : SELU_ALPHA * expm1f(x));
}

struct GP {
    float ox, oy, oz, ihx, ihy, ihz, hmin2, pad;
    int Gx, Gy, Gz, maxG;
};

// ---------- dense matmul: Y[N,128] = concat(src, P[N,3]?) @ W ----------
// If INTERP, the input row gr is knn-interpolated on the fly from X via
// kidx/kw (bit-identical to the separate k_interp pass).
template<int FIC, bool HAS_POS, bool BIAS_SELU, bool ROWSCALE, bool INTERP>
__global__ __launch_bounds__(256) void k_matmul128(
    const float* __restrict__ X, const float* __restrict__ P,
    const float* __restrict__ W, const float* __restrict__ bias,
    const float* __restrict__ rs,
    const int* __restrict__ kidx, const float* __restrict__ kw,
    float* __restrict__ Y, int N)
{
    constexpr int ICT = FIC + (HAS_POS ? 3 : 0);
    __shared__ float xs[16][ICT + 1];
    int row0 = blockIdx.x * 16;

    for (int idx = threadIdx.x; idx < 16 * FIC; idx += 256) {
        int r = idx / FIC, c = idx % FIC;
        int gr = row0 + r;
        float v = 0.0f;
        if (gr < N) {
            if (INTERP) {
                int i0 = kidx[gr * 3], i1 = kidx[gr * 3 + 1], i2 = kidx[gr * 3 + 2];
                float w0 = kw[gr * 4], w1 = kw[gr * 4 + 1], w2 = kw[gr * 4 + 2];
                float inv = 1.0f / kw[gr * 4 + 3];
                float num = w0 * X[(size_t)i0 * FIC + c] + w1 * X[(size_t)i1 * FIC + c]
                          + w2 * X[(size_t)i2 * FIC + c];
                v = num * inv;
            } else {
                v = X[(size_t)gr * FIC + c];
            }
        }
        xs[r][c] = v;
    }
    if (HAS_POS) {
        for (int idx = threadIdx.x; idx < 16 * 3; idx += 256) {
            int r = idx / 3, c = idx % 3;
            int gr = row0 + r;
            xs[r][FIC + c] = (gr < N) ? P[gr * 3 + c] : 0.0f;
        }
    }
    __syncthreads();

    int col = threadIdx.x & 127;
    int half = threadIdx.x >> 7;
    float acc[8];
#pragma unroll
    for (int r = 0; r < 8; ++r) acc[r] = 0.0f;

#pragma unroll 4
    for (int i = 0; i < ICT; ++i) {
        float wv = W[i * 128 + col];
#pragma unroll
        for (int r = 0; r < 8; ++r)
            acc[r] = fmaf(xs[half * 8 + r][i], wv, acc[r]);
    }

    float bv = BIAS_SELU ? bias[col] : 0.0f;
#pragma unroll
    for (int r = 0; r < 8; ++r) {
        int gr = row0 + half * 8 + r;
        if (gr < N) {
            float v = acc[r];
            if (BIAS_SELU) v = selu_f(v + bv);
            if (ROWSCALE) v *= rs[gr];
            Y[(size_t)gr * 128 + col] = v;
        }
    }
}

// ---------- batched triple graph build (all levels at once) ----------
__global__ void k_hist3(const int* __restrict__ c0, int E0, int* __restrict__ n0,
                        const int* __restrict__ c1, int E1, int* __restrict__ n1,
                        const int* __restrict__ c2, int E2, int* __restrict__ n2) {
    int i = blockIdx.x * 256 + threadIdx.x;
    if (i < E0) atomicAdd(&n0[c0[i]], 1);
    else if (i < E0 + E1) atomicAdd(&n1[c1[i - E0]], 1);
    else if (i < E0 + E1 + E2) atomicAdd(&n2[c2[i - E0 - E1]], 1);
}

__global__ __launch_bounds__(256) void k_scan1t(
    const int* __restrict__ in0, int* __restrict__ out0, float* __restrict__ dva, int n0a,
    const int* __restrict__ in1, int* __restrict__ out1, float* __restrict__ dvb, int n1a,
    const int* __restrict__ in2, int* __restrict__ out2, float* __restrict__ dvc, int n2a,
    int* __restrict__ bsum, int nbmax)
{
    int y = blockIdx.y;
    const int* in = y == 0 ? in0 : (y == 1 ? in1 : in2);
    int* out = y == 0 ? out0 : (y == 1 ? out1 : out2);
    float* dv = y == 0 ? dva : (y == 1 ? dvb : dvc);
    int n = y == 0 ? n0a : (y == 1 ? n1a : n2a);
    __shared__ int s[256];
    int tid = threadIdx.x;
    int base = blockIdx.x * 1024 + tid * 4;
    int a[4];
#pragma unroll
    for (int k = 0; k < 4; ++k) a[k] = (base + k < n) ? in[base + k] : 0;
#pragma unroll
    for (int k = 0; k < 4; ++k)
        if (base + k < n) dv[base + k] = rsqrtf((float)a[k] + 1.0f);
    int t = a[0] + a[1] + a[2] + a[3];
    s[tid] = t;
    __syncthreads();
    for (int off = 1; off < 256; off <<= 1) {
        int x = (tid >= off) ? s[tid - off] : 0;
        __syncthreads();
        s[tid] += x;
        __syncthreads();
    }
    int run = s[tid] - t;
#pragma unroll
    for (int k = 0; k < 4; ++k) {
        if (base + k < n) out[base + k] = run;
        run += a[k];
    }
    if (tid == 255) bsum[y * nbmax + blockIdx.x] = s[255];
}

__global__ void k_scan2(int* __restrict__ bsum, int nb) {
    if (threadIdx.x == 0) {
        int* b = bsum + blockIdx.x * nb;
        int run = 0;
        for (int i = 0; i < nb; ++i) { int v = b[i]; b[i] = run; run += v; }
    }
}

__global__ void k_scan3t(int* __restrict__ rp0, int* __restrict__ cu0, int E0, int n0a,
                         int* __restrict__ rp1, int* __restrict__ cu1, int E1, int n1a,
                         int* __restrict__ rp2, int* __restrict__ cu2, int E2, int n2a,
                         const int* __restrict__ bsum, int nbmax) {
    int y = blockIdx.y;
    int* rp = y == 0 ? rp0 : (y == 1 ? rp1 : rp2);
    int* cu = y == 0 ? cu0 : (y == 1 ? cu1 : cu2);
    int E = y == 0 ? E0 : (y == 1 ? E1 : E2);
    int n = y == 0 ? n0a : (y == 1 ? n1a : n2a);
    const int* bs = bsum + y * nbmax;
    int i = blockIdx.x * 256 + threadIdx.x;
    if (i < n) {
        int v = rp[i] + bs[i >> 10];
        rp[i] = v;
        cu[i] = v;
    }
    if (i == 0) rp[n] = E;
}

__global__ void k_scatter3(const int* __restrict__ ei0, int E0, int* __restrict__ cu0, int* __restrict__ cs0,
                           const int* __restrict__ ei1, int E1, int* __restrict__ cu1, int* __restrict__ cs1,
                           const int* __restrict__ ei2, int E2, int* __restrict__ cu2, int* __restrict__ cs2) {
    int i = blockIdx.x * 256 + threadIdx.x;
    const int* ei; int E; int* cur; int* csr; int e;
    if (i < E0)               { ei = ei0; E = E0; cur = cu0; csr = cs0; e = i; }
    else if (i < E0 + E1)     { ei = ei1; E = E1; cur = cu1; csr = cs1; e = i - E0; }
    else if (i < E0 + E1 + E2){ ei = ei2; E = E2; cur = cu2; csr = cs2; e = i - E0 - E1; }
    else return;
    int r = ei[e], c = ei[E + e];
    int p = atomicAdd(&cur[c], 1);
    csr[p] = r;
}

// ---------- CSR gather aggregation, float4-vectorized (32 thr/node) ----------
__global__ __launch_bounds__(256) void k_gather128(
    const int* __restrict__ rowptr, const int* __restrict__ csr,
    const float4* __restrict__ xws4, const float* __restrict__ dv,
    const float4* __restrict__ bias4, float4* __restrict__ out4, int N)
{
    int t = blockIdx.x * 256 + threadIdx.x;
    int node = t >> 5, c4 = t & 31;
    if (node >= N) return;
    int s = rowptr[node], e = rowptr[node + 1];
    float4 acc = xws4[(size_t)node * 32 + c4];  // self loop (already *dinv[node])
    for (int i = s; i < e; ++i) {
        int src = csr[i];
        float4 v = xws4[(size_t)src * 32 + c4];
        acc.x += v.x; acc.y += v.y; acc.z += v.z; acc.w += v.w;
    }
    float d = dv[node];
    float4 b = bias4[c4];
    float4 o;
    o.x = selu_f(fmaf(acc.x, d, b.x));
    o.y = selu_f(fmaf(acc.y, d, b.y));
    o.z = selu_f(fmaf(acc.z, d, b.z));
    o.w = selu_f(fmaf(acc.w, d, b.w));
    out4[(size_t)node * 32 + c4] = o;
}

__global__ __launch_bounds__(256) void k_gather5(
    const int* __restrict__ rowptr, const int* __restrict__ csr,
    const float* __restrict__ xws, const float* __restrict__ dv,
    const float* __restrict__ bias, float* __restrict__ out, int N)
{
    int t = blockIdx.x * 256 + threadIdx.x;
    int node = t >> 3, ch = t & 7;
    if (node >= N || ch >= 5) return;
    int s = rowptr[node], e = rowptr[node + 1];
    float acc = xws[(size_t)node * 5 + ch];
    for (int i = s; i < e; ++i) {
        int src = csr[i];
        acc += xws[(size_t)src * 5 + ch];
    }
    out[(size_t)node * 5 + ch] = acc * dv[node] + bias[ch];
}

// ---------- onera transform (all 3 levels fused); emits {x,y,z,|p|^2} ----------
__global__ void k_transform3(const float* __restrict__ p0, float4* __restrict__ t0, int n0,
                             const float* __restrict__ p1, float4* __restrict__ t1, int n1,
                             const float* __restrict__ p2, float4* __restrict__ t2, int n2) {
    int i = blockIdx.x * 256 + threadIdx.x;
    const float* pos; float4* tp; int li;
    if (i < n0) { pos = p0; tp = t0; li = i; }
    else if (i < n0 + n1) { pos = p1; tp = t1; li = i - n0; }
    else if (i < n0 + n1 + n2) { pos = p2; tp = t2; li = i - n0 - n1; }
    else return;
    float x = pos[li * 3 + 0], y = pos[li * 3 + 1], z = pos[li * 3 + 2];
    float nx = x - TAN30f * y;
    float f = 1.0f + (1.0f / 0.56f - 1.0f) * (y / 1.1963f);
    float X = nx * f, Y = y * f, Z = z * f;
    tp[li] = make_float4(X, Y, Z, (X * X + Y * Y) + Z * Z);
}

// ---------- spatial grid kNN (both levels fused) ----------
__global__ __launch_bounds__(256) void k_bbox2(const float4* __restrict__ tpa, int na,
                                               const float4* __restrict__ tpb, int nb,
                                               float* __restrict__ bbp) {
    const float4* tp = blockIdx.y ? tpb : tpa;
    int n = blockIdx.y ? nb : na;
    __shared__ float red[6][256];
    float mn0 = 3.4e38f, mn1 = 3.4e38f, mn2 = 3.4e38f;
    float mx0 = -3.4e38f, mx1 = -3.4e38f, mx2 = -3.4e38f;
    for (int i = blockIdx.x * 256 + threadIdx.x; i < n; i += gridDim.x * 256) {
        float4 t = tp[i];
        mn0 = fminf(mn0, t.x); mx0 = fmaxf(mx0, t.x);
        mn1 = fminf(mn1, t.y); mx1 = fmaxf(mx1, t.y);
        mn2 = fminf(mn2, t.z); mx2 = fmaxf(mx2, t.z);
    }
    int tid = threadIdx.x;
    red[0][tid] = mn0; red[1][tid] = mn1; red[2][tid] = mn2;
    red[3][tid] = mx0; red[4][tid] = mx1; red[5][tid] = mx2;
    __syncthreads();
    for (int off = 128; off > 0; off >>= 1) {
        if (tid < off) {
#pragma unroll
            for (int k = 0; k < 3; ++k) {
                red[k][tid] = fminf(red[k][tid], red[k][tid + off]);
                red[3 + k][tid] = fmaxf(red[3 + k][tid], red[3 + k][tid + off]);
            }
        }
        __syncthreads();
    }
    if (tid == 0) {
        float* o = bbp + (blockIdx.y * BBOXBLK + blockIdx.x) * 6;
#pragma unroll
        for (int k = 0; k < 3; ++k) {
            o[k] = red[k][0];
            o[3 + k] = red[3 + k][0];
        }
    }
}

__global__ void k_gridparams2(const float* __restrict__ bbp, int na, int nb,
                              GP* __restrict__ gps) {
    if (threadIdx.x != 0) return;
    int set = blockIdx.x;
    const float* bp = bbp + set * BBOXBLK * 6;
    int n = set ? nb : na;
    GP* gp = gps + set;
    float mn[3] = {3.4e38f, 3.4e38f, 3.4e38f};
    float mx[3] = {-3.4e38f, -3.4e38f, -3.4e38f};
    for (int i = 0; i < BBOXBLK; ++i) {
#pragma unroll
        for (int k = 0; k < 3; ++k) {
            mn[k] = fminf(mn[k], bp[i * 6 + k]);
            mx[k] = fmaxf(mx[k], bp[i * 6 + 3 + k]);
        }
    }
    float e[3], o[3];
#pragma unroll
    for (int k = 0; k < 3; ++k) {
        float ext = fmaxf(mx[k] - mn[k], 1e-6f);
        float padv = ext * 1e-4f + 1e-6f;
        o[k] = mn[k] - padv;
        e[k] = ext + 2.0f * padv;
    }
    float T = (float)n * PPC_T;
    float s = cbrtf(T / (e[0] * e[1] * e[2]));
    int G[3];
#pragma unroll
    for (int k = 0; k < 3; ++k) {
        int g = (int)ceilf(e[k] * s);
        G[k] = g < 1 ? 1 : (g > MAXG ? MAXG : g);
    }
    float h[3];
#pragma unroll
    for (int k = 0; k < 3; ++k) h[k] = e[k] / (float)G[k];
    float hmin = fminf(h[0], fminf(h[1], h[2]));
    gp->ox = o[0]; gp->oy = o[1]; gp->oz = o[2];
    gp->ihx = (float)G[0] / e[0]; gp->ihy = (float)G[1] / e[1]; gp->ihz = (float)G[2] / e[2];
    gp->hmin2 = hmin * hmin;
    gp->Gx = G[0]; gp->Gy = G[1]; gp->Gz = G[2];
    gp->maxG = max(G[0], max(G[1], G[2]));
}

__device__ __forceinline__ int cell_of(float4 t, const GP* gp) {
    int cx = min(max((int)((t.x - gp->ox) * gp->ihx), 0), gp->Gx - 1);
    int cy = min(max((int)((t.y - gp->oy) * gp->ihy), 0), gp->Gy - 1);
    int cz = min(max((int)((t.z - gp->oz) * gp->ihz), 0), gp->Gz - 1);
    return (cz * gp->Gy + cy) * gp->Gx + cx;
}

// 4 segments: ref0 (tp0,gp0) | q1 (tp1,gp0) | ref1 (tp1,gp1) | q2 (tp2,gp1)
__global__ void k_cellid4(const float4* __restrict__ tp0, int N0,
                          const float4* __restrict__ tp1, int N1,
                          const float4* __restrict__ tp2, int N2,
                          int* __restrict__ gcell0, int* __restrict__ qcell1,
                          int* __restrict__ gcell1, int* __restrict__ qcell2,
                          int* __restrict__ cnt, const GP* __restrict__ gps) {
    int i = blockIdx.x * 256 + threadIdx.x;
    const float4* tp; const GP* gp; int* cellout; int* cn; int li;
    if (i < N0)                { tp = tp0; gp = gps;     cellout = gcell0; cn = cnt;            li = i; }
    else if (i < N0 + N1)      { tp = tp1; gp = gps;     cellout = qcell1; cn = cnt + MAXC;     li = i - N0; }
    else if (i < N0 + 2 * N1)  { tp = tp1; gp = gps + 1; cellout = gcell1; cn = cnt + 2 * MAXC; li = i - N0 - N1; }
    else if (i < N0 + 2 * N1 + N2) { tp = tp2; gp = gps + 1; cellout = qcell2; cn = cnt + 3 * MAXC; li = i - N0 - 2 * N1; }
    else return;
    int cid = cell_of(tp[li], gp);
    cellout[li] = cid;
    atomicAdd(&cn[cid], 1);
}

__global__ __launch_bounds__(256) void k_scan1c(const int* __restrict__ cnt,
                                                int* __restrict__ row,
                                                int* __restrict__ bsum, int nb) {
    const int* in = cnt + blockIdx.y * MAXC;
    int* out = row + blockIdx.y * (MAXC + 1);
    __shared__ int s[256];
    int tid = threadIdx.x;
    int base = blockIdx.x * 1024 + tid * 4;
    int a[4];
#pragma unroll
    for (int k = 0; k < 4; ++k) a[k] = (base + k < MAXC) ? in[base + k] : 0;
    int t = a[0] + a[1] + a[2] + a[3];
    s[tid] = t;
    __syncthreads();
    for (int off = 1; off < 256; off <<= 1) {
        int x = (tid >= off) ? s[tid - off] : 0;
        __syncthreads();
        s[tid] += x;
        __syncthreads();
    }
    int run = s[tid] - t;
#pragma unroll
    for (int k = 0; k < 4; ++k) {
        if (base + k < MAXC) out[base + k] = run;
        run += a[k];
    }
    if (tid == 255) bsum[blockIdx.y * nb + blockIdx.x] = s[255];
}

__global__ void k_scan3c(int* __restrict__ row, int* __restrict__ cur,
                         const int* __restrict__ bsum, int nb, int4 E4) {
    int y = blockIdx.y;
    int* rp = row + y * (MAXC + 1);
    int* cu = cur + y * MAXC;
    const int* bs = bsum + y * nb;
    int E = (y == 0) ? E4.x : (y == 1) ? E4.y : (y == 2) ? E4.z : E4.w;
    int i = blockIdx.x * 256 + threadIdx.x;
    if (i < MAXC) {
        int v = rp[i] + bs[i >> 10];
        rp[i] = v;
        cu[i] = v;
    }
    if (i == 0) rp[MAXC] = E;
}

__global__ void k_scatter4(const float4* __restrict__ tp0, int N0,
                           const float4* __restrict__ tp1, int N1,
                           const float4* __restrict__ tp2, int N2,
                           const int* __restrict__ gcell0, const int* __restrict__ qcell1,
                           const int* __restrict__ gcell1, const int* __restrict__ qcell2,
                           int* __restrict__ cur,
                           float4* __restrict__ gpts0, float4* __restrict__ gpts1,
                           int* __restrict__ qorder1, int* __restrict__ qorder2) {
    int i = blockIdx.x * 256 + threadIdx.x;
    if (i < N0) {
        int p = atomicAdd(&cur[gcell0[i]], 1);
        float4 t = tp0[i];
        t.w = __int_as_float(i);
        gpts0[p] = t;
    } else if (i < N0 + N1) {
        int j = i - N0;
        int p = atomicAdd(&cur[MAXC + qcell1[j]], 1);
        qorder1[p] = j;
    } else if (i < N0 + 2 * N1) {
        int j = i - N0 - N1;
        int p = atomicAdd(&cur[2 * MAXC + gcell1[j]], 1);
        float4 t = tp1[j];
        t.w = __int_as_float(j);
        gpts1[p] = t;
    } else if (i < N0 + 2 * N1 + N2) {
        int j = i - N0 - 2 * N1;
        int p = atomicAdd(&cur[3 * MAXC + qcell2[j]], 1);
        qorder2[p] = j;
    }
}

// Both levels' searches in one launch; point scan unrolled x4 (proven
// R13 config — x8 spills to scratch, WRITE_SIZE 10->32 MB, regressed).
__global__ __launch_bounds__(256) void k_knn_grid2(
    const float4* __restrict__ tpq1, int N1, const int* __restrict__ qorder1,
    const float4* __restrict__ gpts0, const int* __restrict__ crow0,
    int* __restrict__ oidx1, float* __restrict__ ow1,
    const float4* __restrict__ tpq2, int N2, const int* __restrict__ qorder2,
    const float4* __restrict__ gpts1, const int* __restrict__ crow1,
    int* __restrict__ oidx2, float* __restrict__ ow2,
    const GP* __restrict__ gps)
{
    int t = blockIdx.x * 256 + threadIdx.x;
    const float4* tpq; const int* qord; const float4* gpts; const int* crow;
    const GP* gp; int* oidx; float* ow; int slot; int Nq;
    if (t < N1) {
        tpq = tpq1; qord = qorder1; gpts = gpts0; crow = crow0;
        gp = gps; oidx = oidx1; ow = ow1; slot = t; Nq = N1;
    } else {
        tpq = tpq2; qord = qorder2; gpts = gpts1; crow = crow1;
        gp = gps + 1; oidx = oidx2; ow = ow2; slot = t - N1; Nq = N2;
    }
    bool active = slot < Nq;
    int qi = active ? qord[slot] : 0;

    float ox = gp->ox, oy = gp->oy, oz = gp->oz;
    float ihx = gp->ihx, ihy = gp->ihy, ihz = gp->ihz;
    float hmin2 = gp->hmin2;
    int Gx = gp->Gx, Gy = gp->Gy, Gz = gp->Gz, maxG = gp->maxG;

    float qx = 0, qy = 0, qz = 0, q2 = 0;
    if (active) { float4 tq = tpq[qi]; qx = tq.x; qy = tq.y; qz = tq.z; q2 = tq.w; }
    int cx = min(max((int)((qx - ox) * ihx), 0), Gx - 1);
    int cy = min(max((int)((qy - oy) * ihy), 0), Gy - 1);
    int cz = min(max((int)((qz - oz) * ihz), 0), Gz - 1);

    float d0 = 3.4e38f, d1 = 3.4e38f, d2 = 3.4e38f;
    int j0 = 0x7FFFFFFF, j1 = 0x7FFFFFFF, j2 = 0x7FFFFFFF;

    auto insert = [&](float d, int id) {
        // lexicographic (d, id) — matches top_k tie order
        if (d < d2 || (d == d2 && id < j2)) {
            if (d < d1 || (d == d1 && id < j1)) {
                d2 = d1; j2 = j1;
                if (d < d0 || (d == d0 && id < j0)) {
                    d1 = d0; j1 = j0; d0 = d; j0 = id;
                } else { d1 = d; j1 = id; }
            } else { d2 = d; j2 = id; }
        }
    };
    auto proc = [&](float4 p) {
        int id = __float_as_int(p.w);
        float px2 = fmaf(p.z, p.z, fmaf(p.y, p.y, p.x * p.x));
        float dot = fmaf(p.z, qz, fmaf(p.y, qy, p.x * qx));
        float d = (q2 - 2.0f * dot) + px2;
        insert(d, id);
    };
    auto scan_range = [&](int s, int e) {
        int i = s;
        for (; i + 3 < e; i += 4) {
            float4 pa = gpts[i], pb = gpts[i + 1], pc = gpts[i + 2], pd = gpts[i + 3];
            proc(pa); proc(pb); proc(pc); proc(pd);
        }
        for (; i < e; ++i) { float4 p = gpts[i]; proc(p); }
    };
    auto scan_cells = [&](int zz, int yy, int xlo, int xhi) {
        int base = (zz * Gy + yy) * Gx;
        scan_range(crow[base + xlo], crow[base + xhi + 1]);
    };

    {
        int xlo = max(cx - 1, 0), xhi = min(cx + 1, Gx - 1);
        int rs[9], re[9];
#pragma unroll
        for (int k = 0; k < 9; ++k) {
            int zz = cz + k / 3 - 1, yy = cy + k % 3 - 1;
            bool ok = active && zz >= 0 && zz < Gz && yy >= 0 && yy < Gy;
            int base = ok ? (zz * Gy + yy) * Gx : 0;
            int a = crow[base + (ok ? xlo : 0)];
            int b = crow[base + (ok ? xhi + 1 : 0)];
            rs[k] = ok ? a : 0;
            re[k] = ok ? b : 0;
        }
#pragma unroll
        for (int k = 0; k < 9; ++k) scan_range(rs[k], re[k]);
    }
    bool done = !active || (d2 < hmin2);   // guarantee radius 1*hmin after r=1 cube

    for (int r = 2; r <= maxG; ++r) {
        if (__all(done)) break;
        if (!done) {
            int xlo = max(cx - r, 0), xhi = min(cx + r, Gx - 1);
            for (int zz = max(cz - r, 0); zz <= min(cz + r, Gz - 1); ++zz)
                for (int yy = max(cy - r, 0); yy <= min(cy + r, Gy - 1); ++yy) {
                    if (max(abs(zz - cz), abs(yy - cy)) == r) {
                        scan_cells(zz, yy, xlo, xhi);        // full edge row
                    } else {
                        if (cx - r >= 0)      scan_cells(zz, yy, cx - r, cx - r);
                        if (cx + r <= Gx - 1) scan_cells(zz, yy, cx + r, cx + r);
                    }
                }
            done = d2 < hmin2 * (float)(r * r);
        }
    }

    if (active) {
        float w0 = 1.0f / fmaxf(d0, 1e-16f);
        float w1 = 1.0f / fmaxf(d1, 1e-16f);
        float w2 = 1.0f / fmaxf(d2, 1e-16f);
        float s = w0 + w1 + w2;
        oidx[qi * 3 + 0] = j0; oidx[qi * 3 + 1] = j1; oidx[qi * 3 + 2] = j2;
        ow[qi * 4 + 0] = w0; ow[qi * 4 + 1] = w1; ow[qi * 4 + 2] = w2; ow[qi * 4 + 3] = s;
    }
}

// ---------- output conv matmul (OC=5), row-scaled by dinv ----------
__global__ __launch_bounds__(256) void k_matmul5(const float* __restrict__ X, const float* __restrict__ P,
                                                 const float* __restrict__ W, const float* __restrict__ rs,
                                                 float* __restrict__ Y, int N) {
    __shared__ float xs[32][132];
    __shared__ float ws[131 * 5];
    int row0 = blockIdx.x * 32;
    for (int idx = threadIdx.x; idx < 131 * 5; idx += 256) ws[idx] = W[idx];
    for (int idx = threadIdx.x; idx < 32 * 128; idx += 256) {
        int r = idx >> 7, c = idx & 127;
        xs[r][c] = X[(size_t)(row0 + r) * 128 + c];
    }
    for (int idx = threadIdx.x; idx < 32 * 3; idx += 256) {
        int r = idx / 3, c = idx % 3;
        xs[r][128 + c] = P[(row0 + r) * 3 + c];
    }
    __syncthreads();
    int r = threadIdx.x >> 3;
    int c = threadIdx.x & 7;
    if (c < 5) {
        float acc = 0.0f;
        for (int i = 0; i < 131; ++i) acc = fmaf(xs[r][i], ws[i * 5 + c], acc);
        Y[(size_t)(row0 + r) * 5 + c] = acc * rs[row0 + r];
    }
}

extern "C" void kernel_launch(void* const* d_in, const int* in_sizes, int n_in,
                              void* d_out, int out_size, void* d_ws, size_t ws_size,
                              hipStream_t stream) {
    const float* latent = (const float*)d_in[0];
    const float* pos0   = (const float*)d_in[1];
    const float* pos1   = (const float*)d_in[2];
    const float* pos2   = (const float*)d_in[3];
    const float* W_lin  = (const float*)d_in[4];
    const float* b_lin  = (const float*)d_in[5];
    const float* W0 = (const float*)d_in[6];  const float* b0 = (const float*)d_in[7];
    const float* W1 = (const float*)d_in[8];  const float* b1 = (const float*)d_in[9];
    const float* W2 = (const float*)d_in[10]; const float* b2 = (const float*)d_in[11];
    const float* W3 = (const float*)d_in[12]; const float* b3 = (const float*)d_in[13];
    const float* W4 = (const float*)d_in[14]; const float* b4 = (const float*)d_in[15];
    const int* ei0 = (const int*)d_in[16];
    const int* ei1 = (const int*)d_in[17];
    const int* ei2 = (const int*)d_in[18];
    float* out = (float*)d_out;

    const int N0 = in_sizes[1] / 3, N1 = in_sizes[2] / 3, N2 = in_sizes[3] / 3;
    const int E0 = in_sizes[16] / 2, E1 = in_sizes[17] / 2, E2 = in_sizes[18] / 2;

    char* wsp = (char*)d_ws;
    auto alloc = [&](size_t bytes) {
        char* p = wsp;
        wsp += (bytes + 255) & ~size_t(255);
        return p;
    };
    float*    A       = (float*)alloc((size_t)N2 * 128 * 4);
    float*    Bb      = (float*)alloc((size_t)N2 * 128 * 4);
    float4*   tp0     = (float4*)alloc((size_t)N0 * 16);
    float4*   tp1     = (float4*)alloc((size_t)N1 * 16);
    float4*   tp2     = (float4*)alloc((size_t)N2 * 16);
    // per-level graph structures (built once, persist)
    float*    dv0     = (float*)alloc((size_t)N0 * 4);
    float*    dv1     = (float*)alloc((size_t)N1 * 4);
    float*    dv2     = (float*)alloc((size_t)N2 * 4);
    int*      cnt012  = (int*)  alloc((size_t)(N0 + N1 + N2) * 4);
    int*      cnt0 = cnt012, *cnt1 = cnt012 + N0, *cnt2 = cnt012 + N0 + N1;
    int*      rp0     = (int*)  alloc(((size_t)N0 + 1) * 4);
    int*      rp1     = (int*)  alloc(((size_t)N1 + 1) * 4);
    int*      rp2     = (int*)  alloc(((size_t)N2 + 1) * 4);
    int*      cur0    = (int*)  alloc((size_t)N0 * 4);
    int*      cur1    = (int*)  alloc((size_t)N1 * 4);
    int*      cur2    = (int*)  alloc((size_t)N2 * 4);
    int*      csr0    = (int*)  alloc((size_t)E0 * 4);
    int*      csr1    = (int*)  alloc((size_t)E1 * 4);
    int*      csr2    = (int*)  alloc((size_t)E2 * 4);
    int*      bsum    = (int*)  alloc(4096);
    float*    xw5     = (float*)alloc((size_t)N2 * 5 * 4);
    float*    bbp     = (float*)alloc((size_t)2 * BBOXBLK * 6 * 4);
    GP*       gps     = (GP*)   alloc(2 * sizeof(GP));
    int*      knncnt  = (int*)  alloc((size_t)4 * MAXC * 4);
    int*      knnrow  = (int*)  alloc((size_t)4 * (MAXC + 1) * 4);
    int*      knncur  = (int*)  alloc((size_t)4 * MAXC * 4);
    int*      gcell0  = (int*)  alloc((size_t)N0 * 4);
    int*      gcell1  = (int*)  alloc((size_t)N1 * 4);
    int*      qcell1  = (int*)  alloc((size_t)N1 * 4);
    int*      qcell2  = (int*)  alloc((size_t)N2 * 4);
    float4*   gpts0   = (float4*)alloc((size_t)N0 * 16);
    float4*   gpts1   = (float4*)alloc((size_t)N1 * 16);
    int*      qorder1 = (int*)  alloc((size_t)N1 * 4);
    int*      qorder2 = (int*)  alloc((size_t)N2 * 4);
    int*      kidx1   = (int*)  alloc((size_t)N1 * 3 * 4);
    float*    kw1     = (float*)alloc((size_t)N1 * 4 * 4);
    int*      kidx2   = (int*)  alloc((size_t)N2 * 3 * 4);
    float*    kw2     = (float*)alloc((size_t)N2 * 4 * 4);

    auto cdiv = [](int a, int b) { return (a + b - 1) / b; };

    // transforms (one launch)
    k_transform3<<<cdiv(N0 + N1 + N2, 256), 256, 0, stream>>>(pos0, tp0, N0, pos1, tp1, N1,
                                                              pos2, tp2, N2);

    // ---- both kNN levels fused ----
    {
        k_bbox2<<<dim3(BBOXBLK, 2), 256, 0, stream>>>(tp0, N0, tp1, N1, bbp);
        k_gridparams2<<<2, 64, 0, stream>>>(bbp, N0, N1, gps);
        hipMemsetAsync(knncnt, 0, (size_t)4 * MAXC * 4, stream);
        int tot = N0 + 2 * N1 + N2;
        k_cellid4<<<cdiv(tot, 256), 256, 0, stream>>>(tp0, N0, tp1, N1, tp2, N2,
                                                      gcell0, qcell1, gcell1, qcell2,
                                                      knncnt, gps);
        int nbc = cdiv(MAXC, 1024);
        k_scan1c<<<dim3(nbc, 4), 256, 0, stream>>>(knncnt, knnrow, bsum, nbc);
        k_scan2<<<4, 64, 0, stream>>>(bsum, nbc);
        k_scan3c<<<dim3(cdiv(MAXC, 256), 4), 256, 0, stream>>>(knnrow, knncur, bsum, nbc,
                                                               make_int4(N0, N1, N1, N2));
        k_scatter4<<<cdiv(tot, 256), 256, 0, stream>>>(tp0, N0, tp1, N1, tp2, N2,
                                                       gcell0, qcell1, gcell1, qcell2,
                                                       knncur, gpts0, gpts1, qorder1, qorder2);
        k_knn_grid2<<<cdiv(N1 + N2, 256), 256, 0, stream>>>(
            tp1, N1, qorder1, gpts0, knnrow, kidx1, kw1,
            tp2, N2, qorder2, gpts1, knnrow + 2 * (MAXC + 1), kidx2, kw2, gps);
    }

    // ---- all three graph builds batched ----
    {
        hipMemsetAsync(cnt012, 0, (size_t)(N0 + N1 + N2) * 4, stream);
        k_hist3<<<cdiv(E0 + E1 + E2, 256), 256, 0, stream>>>(ei0 + E0, E0, cnt0,
                                                             ei1 + E1, E1, cnt1,
                                                             ei2 + E2, E2, cnt2);
        int nbmax = cdiv(N2, 1024);
        k_scan1t<<<dim3(nbmax, 3), 256, 0, stream>>>(cnt0, rp0, dv0, N0,
                                                     cnt1, rp1, dv1, N1,
                                                     cnt2, rp2, dv2, N2, bsum, nbmax);
        k_scan2<<<3, 64, 0, stream>>>(bsum, nbmax);
        k_scan3t<<<dim3(cdiv(N2, 256), 3), 256, 0, stream>>>(rp0, cur0, E0, N0,
                                                             rp1, cur1, E1, N1,
                                                             rp2, cur2, E2, N2, bsum, nbmax);
        k_scatter3<<<cdiv(E0 + E1 + E2, 256), 256, 0, stream>>>(ei0, E0, cur0, csr0,
                                                                ei1, E1, cur1, csr1,
                                                                ei2, E2, cur2, csr2);
    }

    // x = selu(latent @ W_lin + b_lin)  -> A
    k_matmul128<64, false, true, false, false><<<cdiv(N0, 16), 256, 0, stream>>>(
        latent, nullptr, W_lin, b_lin, nullptr, nullptr, nullptr, A, N0);

    // level 0: two convs (A -> A)
    k_matmul128<128, true, false, true, false><<<cdiv(N0, 16), 256, 0, stream>>>(
        A, pos0, W0, nullptr, dv0, nullptr, nullptr, Bb, N0);
    k_gather128<<<cdiv(N0 * 32, 256), 256, 0, stream>>>(rp0, csr0, (const float4*)Bb, dv0,
                                                        (const float4*)b0, (float4*)A, N0);
    k_matmul128<128, true, false, true, false><<<cdiv(N0, 16), 256, 0, stream>>>(
        A, pos0, W1, nullptr, dv0, nullptr, nullptr, Bb, N0);
    k_gather128<<<cdiv(N0 * 32, 256), 256, 0, stream>>>(rp0, csr0, (const float4*)Bb, dv0,
                                                        (const float4*)b1, (float4*)A, N0);

    // level 1 conv with fused interp from level-0 features in A (kidx1/kw1)
    k_matmul128<128, true, false, true, true><<<cdiv(N1, 16), 256, 0, stream>>>(
        A, pos1, W2, nullptr, dv1, kidx1, kw1, Bb, N1);
    k_gather128<<<cdiv(N1 * 32, 256), 256, 0, stream>>>(rp1, csr1, (const float4*)Bb, dv1,
                                                        (const float4*)b2, (float4*)A, N1);

    // level 2 conv with fused interp from level-1 features in A (kidx2/kw2)
    k_matmul128<128, true, false, true, true><<<cdiv(N2, 16), 256, 0, stream>>>(
        A, pos2, W3, nullptr, dv2, kidx2, kw2, Bb, N2);
    k_gather128<<<cdiv(N2 * 32, 256), 256, 0, stream>>>(rp2, csr2, (const float4*)Bb, dv2,
                                                        (const float4*)b3, (float4*)A, N2);

    // output conv (OC=5)
    k_matmul5<<<cdiv(N2, 32), 256, 0, stream>>>(A, pos2, W4, dv2, xw5, N2);
    k_gather5<<<cdiv(N2 * 8, 256), 256, 0, stream>>>(rp2, csr2, xw5, dv2, b4, out, N2);
}

// Round 18
// 814.301 us; speedup vs baseline: 1.2655x; 1.0211x over previous
//
#include <hip/hip_runtime.h>
#include <math.h>

#define TAN30f 0.57735026918962576f
#define SELU_SCALE 1.0507009873554805f
#define SELU_ALPHA 1.6732632423543772f

#define MAXC 65536   // max grid cells
#define MAXG 40
#define BBOXBLK 64
#define PPC_T 0.8f   // target ~1.25 pts/cell; r=1 ball holds ~5.2 expected (>3)

__device__ __forceinline__ float selu_f(float x) {
    return SELU_SCALE * (x > 0.0f ? x : SELU_ALPHA * expm1f(x));
}

struct GP {
    float ox, oy, oz, ihx, ihy, ihz, hmin2, pad;
    int Gx, Gy, Gz, maxG;
};

// ---------- dense matmul: Y[N,128] = concat(src, P[N,3]?) @ W ----------
template<int FIC, bool HAS_POS, bool BIAS_SELU, bool ROWSCALE, bool INTERP>
__global__ __launch_bounds__(256) void k_matmul128(
    const float* __restrict__ X, const float* __restrict__ P,
    const float* __restrict__ W, const float* __restrict__ bias,
    const float* __restrict__ rs,
    const int* __restrict__ kidx, const float* __restrict__ kw,
    float* __restrict__ Y, int N)
{
    constexpr int ICT = FIC + (HAS_POS ? 3 : 0);
    __shared__ float xs[16][ICT + 1];
    int row0 = blockIdx.x * 16;

    for (int idx = threadIdx.x; idx < 16 * FIC; idx += 256) {
        int r = idx / FIC, c = idx % FIC;
        int gr = row0 + r;
        float v = 0.0f;
        if (gr < N) {
            if (INTERP) {
                int i0 = kidx[gr * 3], i1 = kidx[gr * 3 + 1], i2 = kidx[gr * 3 + 2];
                float w0 = kw[gr * 4], w1 = kw[gr * 4 + 1], w2 = kw[gr * 4 + 2];
                float inv = 1.0f / kw[gr * 4 + 3];
                float num = w0 * X[(size_t)i0 * FIC + c] + w1 * X[(size_t)i1 * FIC + c]
                          + w2 * X[(size_t)i2 * FIC + c];
                v = num * inv;
            } else {
                v = X[(size_t)gr * FIC + c];
            }
        }
        xs[r][c] = v;
    }
    if (HAS_POS) {
        for (int idx = threadIdx.x; idx < 16 * 3; idx += 256) {
            int r = idx / 3, c = idx % 3;
            int gr = row0 + r;
            xs[r][FIC + c] = (gr < N) ? P[gr * 3 + c] : 0.0f;
        }
    }
    __syncthreads();

    int col = threadIdx.x & 127;
    int half = threadIdx.x >> 7;
    float acc[8];
#pragma unroll
    for (int r = 0; r < 8; ++r) acc[r] = 0.0f;

#pragma unroll 4
    for (int i = 0; i < ICT; ++i) {
        float wv = W[i * 128 + col];
#pragma unroll
        for (int r = 0; r < 8; ++r)
            acc[r] = fmaf(xs[half * 8 + r][i], wv, acc[r]);
    }

    float bv = BIAS_SELU ? bias[col] : 0.0f;
#pragma unroll
    for (int r = 0; r < 8; ++r) {
        int gr = row0 + half * 8 + r;
        if (gr < N) {
            float v = acc[r];
            if (BIAS_SELU) v = selu_f(v + bv);
            if (ROWSCALE) v *= rs[gr];
            Y[(size_t)gr * 128 + col] = v;
        }
    }
}

// ---------- batched triple graph build (all levels at once) ----------
__global__ void k_hist3(const int* __restrict__ c0, int E0, int* __restrict__ n0,
                        const int* __restrict__ c1, int E1, int* __restrict__ n1,
                        const int* __restrict__ c2, int E2, int* __restrict__ n2) {
    int i = blockIdx.x * 256 + threadIdx.x;
    if (i < E0) atomicAdd(&n0[c0[i]], 1);
    else if (i < E0 + E1) atomicAdd(&n1[c1[i - E0]], 1);
    else if (i < E0 + E1 + E2) atomicAdd(&n2[c2[i - E0 - E1]], 1);
}

__global__ __launch_bounds__(256) void k_scan1t(
    const int* __restrict__ in0, int* __restrict__ out0, float* __restrict__ dva, int n0a,
    const int* __restrict__ in1, int* __restrict__ out1, float* __restrict__ dvb, int n1a,
    const int* __restrict__ in2, int* __restrict__ out2, float* __restrict__ dvc, int n2a,
    int* __restrict__ bsum, int nbmax)
{
    int y = blockIdx.y;
    const int* in = y == 0 ? in0 : (y == 1 ? in1 : in2);
    int* out = y == 0 ? out0 : (y == 1 ? out1 : out2);
    float* dv = y == 0 ? dva : (y == 1 ? dvb : dvc);
    int n = y == 0 ? n0a : (y == 1 ? n1a : n2a);
    __shared__ int s[256];
    int tid = threadIdx.x;
    int base = blockIdx.x * 1024 + tid * 4;
    int a[4];
#pragma unroll
    for (int k = 0; k < 4; ++k) a[k] = (base + k < n) ? in[base + k] : 0;
#pragma unroll
    for (int k = 0; k < 4; ++k)
        if (base + k < n) dv[base + k] = rsqrtf((float)a[k] + 1.0f);
    int t = a[0] + a[1] + a[2] + a[3];
    s[tid] = t;
    __syncthreads();
    for (int off = 1; off < 256; off <<= 1) {
        int x = (tid >= off) ? s[tid - off] : 0;
        __syncthreads();
        s[tid] += x;
        __syncthreads();
    }
    int run = s[tid] - t;
#pragma unroll
    for (int k = 0; k < 4; ++k) {
        if (base + k < n) out[base + k] = run;
        run += a[k];
    }
    if (tid == 255) bsum[y * nbmax + blockIdx.x] = s[255];
}

__global__ void k_scan2(int* __restrict__ bsum, int nb) {
    if (threadIdx.x == 0) {
        int* b = bsum + blockIdx.x * nb;
        int run = 0;
        for (int i = 0; i < nb; ++i) { int v = b[i]; b[i] = run; run += v; }
    }
}

__global__ void k_scan3t(int* __restrict__ rp0, int* __restrict__ cu0, int E0, int n0a,
                         int* __restrict__ rp1, int* __restrict__ cu1, int E1, int n1a,
                         int* __restrict__ rp2, int* __restrict__ cu2, int E2, int n2a,
                         const int* __restrict__ bsum, int nbmax) {
    int y = blockIdx.y;
    int* rp = y == 0 ? rp0 : (y == 1 ? rp1 : rp2);
    int* cu = y == 0 ? cu0 : (y == 1 ? cu1 : cu2);
    int E = y == 0 ? E0 : (y == 1 ? E1 : E2);
    int n = y == 0 ? n0a : (y == 1 ? n1a : n2a);
    const int* bs = bsum + y * nbmax;
    int i = blockIdx.x * 256 + threadIdx.x;
    if (i < n) {
        int v = rp[i] + bs[i >> 10];
        rp[i] = v;
        cu[i] = v;
    }
    if (i == 0) rp[n] = E;
}

__global__ void k_scatter3(const int* __restrict__ ei0, int E0, int* __restrict__ cu0, int* __restrict__ cs0,
                           const int* __restrict__ ei1, int E1, int* __restrict__ cu1, int* __restrict__ cs1,
                           const int* __restrict__ ei2, int E2, int* __restrict__ cu2, int* __restrict__ cs2) {
    int i = blockIdx.x * 256 + threadIdx.x;
    const int* ei; int E; int* cur; int* csr; int e;
    if (i < E0)               { ei = ei0; E = E0; cur = cu0; csr = cs0; e = i; }
    else if (i < E0 + E1)     { ei = ei1; E = E1; cur = cu1; csr = cs1; e = i - E0; }
    else if (i < E0 + E1 + E2){ ei = ei2; E = E2; cur = cu2; csr = cs2; e = i - E0 - E1; }
    else return;
    int r = ei[e], c = ei[E + e];
    int p = atomicAdd(&cur[c], 1);
    csr[p] = r;
}

// ---------- CSR gather aggregation, float4-vectorized (32 thr/node) ----------
// Edge loop batched x4: 4 independent csr+row loads in flight, accumulated
// in original order (bit-identical FP result).
__global__ __launch_bounds__(256) void k_gather128(
    const int* __restrict__ rowptr, const int* __restrict__ csr,
    const float4* __restrict__ xws4, const float* __restrict__ dv,
    const float4* __restrict__ bias4, float4* __restrict__ out4, int N)
{
    int t = blockIdx.x * 256 + threadIdx.x;
    int node = t >> 5, c4 = t & 31;
    if (node >= N) return;
    int s = rowptr[node], e = rowptr[node + 1];
    float4 acc = xws4[(size_t)node * 32 + c4];  // self loop (already *dinv[node])
    int i = s;
    for (; i + 3 < e; i += 4) {
        int s0 = csr[i], s1 = csr[i + 1], s2 = csr[i + 2], s3 = csr[i + 3];
        float4 v0 = xws4[(size_t)s0 * 32 + c4];
        float4 v1 = xws4[(size_t)s1 * 32 + c4];
        float4 v2 = xws4[(size_t)s2 * 32 + c4];
        float4 v3 = xws4[(size_t)s3 * 32 + c4];
        acc.x += v0.x; acc.y += v0.y; acc.z += v0.z; acc.w += v0.w;
        acc.x += v1.x; acc.y += v1.y; acc.z += v1.z; acc.w += v1.w;
        acc.x += v2.x; acc.y += v2.y; acc.z += v2.z; acc.w += v2.w;
        acc.x += v3.x; acc.y += v3.y; acc.z += v3.z; acc.w += v3.w;
    }
    for (; i < e; ++i) {
        int src = csr[i];
        float4 v = xws4[(size_t)src * 32 + c4];
        acc.x += v.x; acc.y += v.y; acc.z += v.z; acc.w += v.w;
    }
    float d = dv[node];
    float4 b = bias4[c4];
    float4 o;
    o.x = selu_f(fmaf(acc.x, d, b.x));
    o.y = selu_f(fmaf(acc.y, d, b.y));
    o.z = selu_f(fmaf(acc.z, d, b.z));
    o.w = selu_f(fmaf(acc.w, d, b.w));
    out4[(size_t)node * 32 + c4] = o;
}

__global__ __launch_bounds__(256) void k_gather5(
    const int* __restrict__ rowptr, const int* __restrict__ csr,
    const float* __restrict__ xws, const float* __restrict__ dv,
    const float* __restrict__ bias, float* __restrict__ out, int N)
{
    int t = blockIdx.x * 256 + threadIdx.x;
    int node = t >> 3, ch = t & 7;
    if (node >= N || ch >= 5) return;
    int s = rowptr[node], e = rowptr[node + 1];
    float acc = xws[(size_t)node * 5 + ch];
    int i = s;
    for (; i + 3 < e; i += 4) {
        int s0 = csr[i], s1 = csr[i + 1], s2 = csr[i + 2], s3 = csr[i + 3];
        float v0 = xws[(size_t)s0 * 5 + ch];
        float v1 = xws[(size_t)s1 * 5 + ch];
        float v2 = xws[(size_t)s2 * 5 + ch];
        float v3 = xws[(size_t)s3 * 5 + ch];
        acc += v0; acc += v1; acc += v2; acc += v3;
    }
    for (; i < e; ++i) {
        int src = csr[i];
        acc += xws[(size_t)src * 5 + ch];
    }
    out[(size_t)node * 5 + ch] = acc * dv[node] + bias[ch];
}

// ---------- onera transform (all 3 levels fused); emits {x,y,z,|p|^2} ----------
__global__ void k_transform3(const float* __restrict__ p0, float4* __restrict__ t0, int n0,
                             const float* __restrict__ p1, float4* __restrict__ t1, int n1,
                             const float* __restrict__ p2, float4* __restrict__ t2, int n2) {
    int i = blockIdx.x * 256 + threadIdx.x;
    const float* pos; float4* tp; int li;
    if (i < n0) { pos = p0; tp = t0; li = i; }
    else if (i < n0 + n1) { pos = p1; tp = t1; li = i - n0; }
    else if (i < n0 + n1 + n2) { pos = p2; tp = t2; li = i - n0 - n1; }
    else return;
    float x = pos[li * 3 + 0], y = pos[li * 3 + 1], z = pos[li * 3 + 2];
    float nx = x - TAN30f * y;
    float f = 1.0f + (1.0f / 0.56f - 1.0f) * (y / 1.1963f);
    float X = nx * f, Y = y * f, Z = z * f;
    tp[li] = make_float4(X, Y, Z, (X * X + Y * Y) + Z * Z);
}

// ---------- spatial grid kNN (both levels fused) ----------
__global__ __launch_bounds__(256) void k_bbox2(const float4* __restrict__ tpa, int na,
                                               const float4* __restrict__ tpb, int nb,
                                               float* __restrict__ bbp) {
    const float4* tp = blockIdx.y ? tpb : tpa;
    int n = blockIdx.y ? nb : na;
    __shared__ float red[6][256];
    float mn0 = 3.4e38f, mn1 = 3.4e38f, mn2 = 3.4e38f;
    float mx0 = -3.4e38f, mx1 = -3.4e38f, mx2 = -3.4e38f;
    for (int i = blockIdx.x * 256 + threadIdx.x; i < n; i += gridDim.x * 256) {
        float4 t = tp[i];
        mn0 = fminf(mn0, t.x); mx0 = fmaxf(mx0, t.x);
        mn1 = fminf(mn1, t.y); mx1 = fmaxf(mx1, t.y);
        mn2 = fminf(mn2, t.z); mx2 = fmaxf(mx2, t.z);
    }
    int tid = threadIdx.x;
    red[0][tid] = mn0; red[1][tid] = mn1; red[2][tid] = mn2;
    red[3][tid] = mx0; red[4][tid] = mx1; red[5][tid] = mx2;
    __syncthreads();
    for (int off = 128; off > 0; off >>= 1) {
        if (tid < off) {
#pragma unroll
            for (int k = 0; k < 3; ++k) {
                red[k][tid] = fminf(red[k][tid], red[k][tid + off]);
                red[3 + k][tid] = fmaxf(red[3 + k][tid], red[3 + k][tid + off]);
            }
        }
        __syncthreads();
    }
    if (tid == 0) {
        float* o = bbp + (blockIdx.y * BBOXBLK + blockIdx.x) * 6;
#pragma unroll
        for (int k = 0; k < 3; ++k) {
            o[k] = red[k][0];
            o[3 + k] = red[3 + k][0];
        }
    }
}

__global__ void k_gridparams2(const float* __restrict__ bbp, int na, int nb,
                              GP* __restrict__ gps) {
    if (threadIdx.x != 0) return;
    int set = blockIdx.x;
    const float* bp = bbp + set * BBOXBLK * 6;
    int n = set ? nb : na;
    GP* gp = gps + set;
    float mn[3] = {3.4e38f, 3.4e38f, 3.4e38f};
    float mx[3] = {-3.4e38f, -3.4e38f, -3.4e38f};
    for (int i = 0; i < BBOXBLK; ++i) {
#pragma unroll
        for (int k = 0; k < 3; ++k) {
            mn[k] = fminf(mn[k], bp[i * 6 + k]);
            mx[k] = fmaxf(mx[k], bp[i * 6 + 3 + k]);
        }
    }
    float e[3], o[3];
#pragma unroll
    for (int k = 0; k < 3; ++k) {
        float ext = fmaxf(mx[k] - mn[k], 1e-6f);
        float padv = ext * 1e-4f + 1e-6f;
        o[k] = mn[k] - padv;
        e[k] = ext + 2.0f * padv;
    }
    float T = (float)n * PPC_T;
    float s = cbrtf(T / (e[0] * e[1] * e[2]));
    int G[3];
#pragma unroll
    for (int k = 0; k < 3; ++k) {
        int g = (int)ceilf(e[k] * s);
        G[k] = g < 1 ? 1 : (g > MAXG ? MAXG : g);
    }
    float h[3];
#pragma unroll
    for (int k = 0; k < 3; ++k) h[k] = e[k] / (float)G[k];
    float hmin = fminf(h[0], fminf(h[1], h[2]));
    gp->ox = o[0]; gp->oy = o[1]; gp->oz = o[2];
    gp->ihx = (float)G[0] / e[0]; gp->ihy = (float)G[1] / e[1]; gp->ihz = (float)G[2] / e[2];
    gp->hmin2 = hmin * hmin;
    gp->Gx = G[0]; gp->Gy = G[1]; gp->Gz = G[2];
    gp->maxG = max(G[0], max(G[1], G[2]));
}

__device__ __forceinline__ int cell_of(float4 t, const GP* gp) {
    int cx = min(max((int)((t.x - gp->ox) * gp->ihx), 0), gp->Gx - 1);
    int cy = min(max((int)((t.y - gp->oy) * gp->ihy), 0), gp->Gy - 1);
    int cz = min(max((int)((t.z - gp->oz) * gp->ihz), 0), gp->Gz - 1);
    return (cz * gp->Gy + cy) * gp->Gx + cx;
}

// 4 segments: ref0 (tp0,gp0) | q1 (tp1,gp0) | ref1 (tp1,gp1) | q2 (tp2,gp1)
__global__ void k_cellid4(const float4* __restrict__ tp0, int N0,
                          const float4* __restrict__ tp1, int N1,
                          const float4* __restrict__ tp2, int N2,
                          int* __restrict__ gcell0, int* __restrict__ qcell1,
                          int* __restrict__ gcell1, int* __restrict__ qcell2,
                          int* __restrict__ cnt, const GP* __restrict__ gps) {
    int i = blockIdx.x * 256 + threadIdx.x;
    const float4* tp; const GP* gp; int* cellout; int* cn; int li;
    if (i < N0)                { tp = tp0; gp = gps;     cellout = gcell0; cn = cnt;            li = i; }
    else if (i < N0 + N1)      { tp = tp1; gp = gps;     cellout = qcell1; cn = cnt + MAXC;     li = i - N0; }
    else if (i < N0 + 2 * N1)  { tp = tp1; gp = gps + 1; cellout = gcell1; cn = cnt + 2 * MAXC; li = i - N0 - N1; }
    else if (i < N0 + 2 * N1 + N2) { tp = tp2; gp = gps + 1; cellout = qcell2; cn = cnt + 3 * MAXC; li = i - N0 - 2 * N1; }
    else return;
    int cid = cell_of(tp[li], gp);
    cellout[li] = cid;
    atomicAdd(&cn[cid], 1);
}

__global__ __launch_bounds__(256) void k_scan1c(const int* __restrict__ cnt,
                                                int* __restrict__ row,
                                                int* __restrict__ bsum, int nb) {
    const int* in = cnt + blockIdx.y * MAXC;
    int* out = row + blockIdx.y * (MAXC + 1);
    __shared__ int s[256];
    int tid = threadIdx.x;
    int base = blockIdx.x * 1024 + tid * 4;
    int a[4];
#pragma unroll
    for (int k = 0; k < 4; ++k) a[k] = (base + k < MAXC) ? in[base + k] : 0;
    int t = a[0] + a[1] + a[2] + a[3];
    s[tid] = t;
    __syncthreads();
    for (int off = 1; off < 256; off <<= 1) {
        int x = (tid >= off) ? s[tid - off] : 0;
        __syncthreads();
        s[tid] += x;
        __syncthreads();
    }
    int run = s[tid] - t;
#pragma unroll
    for (int k = 0; k < 4; ++k) {
        if (base + k < MAXC) out[base + k] = run;
        run += a[k];
    }
    if (tid == 255) bsum[blockIdx.y * nb + blockIdx.x] = s[255];
}

__global__ void k_scan3c(int* __restrict__ row, int* __restrict__ cur,
                         const int* __restrict__ bsum, int nb, int4 E4) {
    int y = blockIdx.y;
    int* rp = row + y * (MAXC + 1);
    int* cu = cur + y * MAXC;
    const int* bs = bsum + y * nb;
    int E = (y == 0) ? E4.x : (y == 1) ? E4.y : (y == 2) ? E4.z : E4.w;
    int i = blockIdx.x * 256 + threadIdx.x;
    if (i < MAXC) {
        int v = rp[i] + bs[i >> 10];
        rp[i] = v;
        cu[i] = v;
    }
    if (i == 0) rp[MAXC] = E;
}

__global__ void k_scatter4(const float4* __restrict__ tp0, int N0,
                           const float4* __restrict__ tp1, int N1,
                           const float4* __restrict__ tp2, int N2,
                           const int* __restrict__ gcell0, const int* __restrict__ qcell1,
                           const int* __restrict__ gcell1, const int* __restrict__ qcell2,
                           int* __restrict__ cur,
                           float4* __restrict__ gpts0, float4* __restrict__ gpts1,
                           int* __restrict__ qorder1, int* __restrict__ qorder2) {
    int i = blockIdx.x * 256 + threadIdx.x;
    if (i < N0) {
        int p = atomicAdd(&cur[gcell0[i]], 1);
        float4 t = tp0[i];
        t.w = __int_as_float(i);
        gpts0[p] = t;
    } else if (i < N0 + N1) {
        int j = i - N0;
        int p = atomicAdd(&cur[MAXC + qcell1[j]], 1);
        qorder1[p] = j;
    } else if (i < N0 + 2 * N1) {
        int j = i - N0 - N1;
        int p = atomicAdd(&cur[2 * MAXC + gcell1[j]], 1);
        float4 t = tp1[j];
        t.w = __int_as_float(j);
        gpts1[p] = t;
    } else if (i < N0 + 2 * N1 + N2) {
        int j = i - N0 - 2 * N1;
        int p = atomicAdd(&cur[3 * MAXC + qcell2[j]], 1);
        qorder2[p] = j;
    }
}

// Both levels' searches in one launch; point scan unrolled x4 (proven
// R13 config — x8 spills to scratch, WRITE_SIZE 10->32 MB, regressed).
__global__ __launch_bounds__(256) void k_knn_grid2(
    const float4* __restrict__ tpq1, int N1, const int* __restrict__ qorder1,
    const float4* __restrict__ gpts0, const int* __restrict__ crow0,
    int* __restrict__ oidx1, float* __restrict__ ow1,
    const float4* __restrict__ tpq2, int N2, const int* __restrict__ qorder2,
    const float4* __restrict__ gpts1, const int* __restrict__ crow1,
    int* __restrict__ oidx2, float* __restrict__ ow2,
    const GP* __restrict__ gps)
{
    int t = blockIdx.x * 256 + threadIdx.x;
    const float4* tpq; const int* qord; const float4* gpts; const int* crow;
    const GP* gp; int* oidx; float* ow; int slot; int Nq;
    if (t < N1) {
        tpq = tpq1; qord = qorder1; gpts = gpts0; crow = crow0;
        gp = gps; oidx = oidx1; ow = ow1; slot = t; Nq = N1;
    } else {
        tpq = tpq2; qord = qorder2; gpts = gpts1; crow = crow1;
        gp = gps + 1; oidx = oidx2; ow = ow2; slot = t - N1; Nq = N2;
    }
    bool active = slot < Nq;
    int qi = active ? qord[slot] : 0;

    float ox = gp->ox, oy = gp->oy, oz = gp->oz;
    float ihx = gp->ihx, ihy = gp->ihy, ihz = gp->ihz;
    float hmin2 = gp->hmin2;
    int Gx = gp->Gx, Gy = gp->Gy, Gz = gp->Gz, maxG = gp->maxG;

    float qx = 0, qy = 0, qz = 0, q2 = 0;
    if (active) { float4 tq = tpq[qi]; qx = tq.x; qy = tq.y; qz = tq.z; q2 = tq.w; }
    int cx = min(max((int)((qx - ox) * ihx), 0), Gx - 1);
    int cy = min(max((int)((qy - oy) * ihy), 0), Gy - 1);
    int cz = min(max((int)((qz - oz) * ihz), 0), Gz - 1);

    float d0 = 3.4e38f, d1 = 3.4e38f, d2 = 3.4e38f;
    int j0 = 0x7FFFFFFF, j1 = 0x7FFFFFFF, j2 = 0x7FFFFFFF;

    auto insert = [&](float d, int id) {
        // lexicographic (d, id) — matches top_k tie order
        if (d < d2 || (d == d2 && id < j2)) {
            if (d < d1 || (d == d1 && id < j1)) {
                d2 = d1; j2 = j1;
                if (d < d0 || (d == d0 && id < j0)) {
                    d1 = d0; j1 = j0; d0 = d; j0 = id;
                } else { d1 = d; j1 = id; }
            } else { d2 = d; j2 = id; }
        }
    };
    auto proc = [&](float4 p) {
        int id = __float_as_int(p.w);
        float px2 = fmaf(p.z, p.z, fmaf(p.y, p.y, p.x * p.x));
        float dot = fmaf(p.z, qz, fmaf(p.y, qy, p.x * qx));
        float d = (q2 - 2.0f * dot) + px2;
        insert(d, id);
    };
    auto scan_range = [&](int s, int e) {
        int i = s;
        for (; i + 3 < e; i += 4) {
            float4 pa = gpts[i], pb = gpts[i + 1], pc = gpts[i + 2], pd = gpts[i + 3];
            proc(pa); proc(pb); proc(pc); proc(pd);
        }
        for (; i < e; ++i) { float4 p = gpts[i]; proc(p); }
    };
    auto scan_cells = [&](int zz, int yy, int xlo, int xhi) {
        int base = (zz * Gy + yy) * Gx;
        scan_range(crow[base + xlo], crow[base + xhi + 1]);
    };

    {
        int xlo = max(cx - 1, 0), xhi = min(cx + 1, Gx - 1);
        int rs[9], re[9];
#pragma unroll
        for (int k = 0; k < 9; ++k) {
            int zz = cz + k / 3 - 1, yy = cy + k % 3 - 1;
            bool ok = active && zz >= 0 && zz < Gz && yy >= 0 && yy < Gy;
            int base = ok ? (zz * Gy + yy) * Gx : 0;
            int a = crow[base + (ok ? xlo : 0)];
            int b = crow[base + (ok ? xhi + 1 : 0)];
            rs[k] = ok ? a : 0;
            re[k] = ok ? b : 0;
        }
#pragma unroll
        for (int k = 0; k < 9; ++k) scan_range(rs[k], re[k]);
    }
    bool done = !active || (d2 < hmin2);   // guarantee radius 1*hmin after r=1 cube

    for (int r = 2; r <= maxG; ++r) {
        if (__all(done)) break;
        if (!done) {
            int xlo = max(cx - r, 0), xhi = min(cx + r, Gx - 1);
            for (int zz = max(cz - r, 0); zz <= min(cz + r, Gz - 1); ++zz)
                for (int yy = max(cy - r, 0); yy <= min(cy + r, Gy - 1); ++yy) {
                    if (max(abs(zz - cz), abs(yy - cy)) == r) {
                        scan_cells(zz, yy, xlo, xhi);        // full edge row
                    } else {
                        if (cx - r >= 0)      scan_cells(zz, yy, cx - r, cx - r);
                        if (cx + r <= Gx - 1) scan_cells(zz, yy, cx + r, cx + r);
                    }
                }
            done = d2 < hmin2 * (float)(r * r);
        }
    }

    if (active) {
        float w0 = 1.0f / fmaxf(d0, 1e-16f);
        float w1 = 1.0f / fmaxf(d1, 1e-16f);
        float w2 = 1.0f / fmaxf(d2, 1e-16f);
        float s = w0 + w1 + w2;
        oidx[qi * 3 + 0] = j0; oidx[qi * 3 + 1] = j1; oidx[qi * 3 + 2] = j2;
        ow[qi * 4 + 0] = w0; ow[qi * 4 + 1] = w1; ow[qi * 4 + 2] = w2; ow[qi * 4 + 3] = s;
    }
}

// ---------- output conv matmul (OC=5), row-scaled by dinv ----------
__global__ __launch_bounds__(256) void k_matmul5(const float* __restrict__ X, const float* __restrict__ P,
                                                 const float* __restrict__ W, const float* __restrict__ rs,
                                                 float* __restrict__ Y, int N) {
    __shared__ float xs[32][132];
    __shared__ float ws[131 * 5];
    int row0 = blockIdx.x * 32;
    for (int idx = threadIdx.x; idx < 131 * 5; idx += 256) ws[idx] = W[idx];
    for (int idx = threadIdx.x; idx < 32 * 128; idx += 256) {
        int r = idx >> 7, c = idx & 127;
        xs[r][c] = X[(size_t)(row0 + r) * 128 + c];
    }
    for (int idx = threadIdx.x; idx < 32 * 3; idx += 256) {
        int r = idx / 3, c = idx % 3;
        xs[r][128 + c] = P[(row0 + r) * 3 + c];
    }
    __syncthreads();
    int r = threadIdx.x >> 3;
    int c = threadIdx.x & 7;
    if (c < 5) {
        float acc = 0.0f;
        for (int i = 0; i < 131; ++i) acc = fmaf(xs[r][i], ws[i * 5 + c], acc);
        Y[(size_t)(row0 + r) * 5 + c] = acc * rs[row0 + r];
    }
}

extern "C" void kernel_launch(void* const* d_in, const int* in_sizes, int n_in,
                              void* d_out, int out_size, void* d_ws, size_t ws_size,
                              hipStream_t stream) {
    const float* latent = (const float*)d_in[0];
    const float* pos0   = (const float*)d_in[1];
    const float* pos1   = (const float*)d_in[2];
    const float* pos2   = (const float*)d_in[3];
    const float* W_lin  = (const float*)d_in[4];
    const float* b_lin  = (const float*)d_in[5];
    const float* W0 = (const float*)d_in[6];  const float* b0 = (const float*)d_in[7];
    const float* W1 = (const float*)d_in[8];  const float* b1 = (const float*)d_in[9];
    const float* W2 = (const float*)d_in[10]; const float* b2 = (const float*)d_in[11];
    const float* W3 = (const float*)d_in[12]; const float* b3 = (const float*)d_in[13];
    const float* W4 = (const float*)d_in[14]; const float* b4 = (const float*)d_in[15];
    const int* ei0 = (const int*)d_in[16];
    const int* ei1 = (const int*)d_in[17];
    const int* ei2 = (const int*)d_in[18];
    float* out = (float*)d_out;

    const int N0 = in_sizes[1] / 3, N1 = in_sizes[2] / 3, N2 = in_sizes[3] / 3;
    const int E0 = in_sizes[16] / 2, E1 = in_sizes[17] / 2, E2 = in_sizes[18] / 2;

    char* wsp = (char*)d_ws;
    auto alloc = [&](size_t bytes) {
        char* p = wsp;
        wsp += (bytes + 255) & ~size_t(255);
        return p;
    };
    float*    A       = (float*)alloc((size_t)N2 * 128 * 4);
    float*    Bb      = (float*)alloc((size_t)N2 * 128 * 4);
    float4*   tp0     = (float4*)alloc((size_t)N0 * 16);
    float4*   tp1     = (float4*)alloc((size_t)N1 * 16);
    float4*   tp2     = (float4*)alloc((size_t)N2 * 16);
    // per-level graph structures (built once, persist)
    float*    dv0     = (float*)alloc((size_t)N0 * 4);
    float*    dv1     = (float*)alloc((size_t)N1 * 4);
    float*    dv2     = (float*)alloc((size_t)N2 * 4);
    int*      cnt012  = (int*)  alloc((size_t)(N0 + N1 + N2) * 4);
    int*      cnt0 = cnt012, *cnt1 = cnt012 + N0, *cnt2 = cnt012 + N0 + N1;
    int*      rp0     = (int*)  alloc(((size_t)N0 + 1) * 4);
    int*      rp1     = (int*)  alloc(((size_t)N1 + 1) * 4);
    int*      rp2     = (int*)  alloc(((size_t)N2 + 1) * 4);
    int*      cur0    = (int*)  alloc((size_t)N0 * 4);
    int*      cur1    = (int*)  alloc((size_t)N1 * 4);
    int*      cur2    = (int*)  alloc((size_t)N2 * 4);
    int*      csr0    = (int*)  alloc((size_t)E0 * 4);
    int*      csr1    = (int*)  alloc((size_t)E1 * 4);
    int*      csr2    = (int*)  alloc((size_t)E2 * 4);
    int*      bsum    = (int*)  alloc(4096);
    float*    xw5     = (float*)alloc((size_t)N2 * 5 * 4);
    float*    bbp     = (float*)alloc((size_t)2 * BBOXBLK * 6 * 4);
    GP*       gps     = (GP*)   alloc(2 * sizeof(GP));
    int*      knncnt  = (int*)  alloc((size_t)4 * MAXC * 4);
    int*      knnrow  = (int*)  alloc((size_t)4 * (MAXC + 1) * 4);
    int*      knncur  = (int*)  alloc((size_t)4 * MAXC * 4);
    int*      gcell0  = (int*)  alloc((size_t)N0 * 4);
    int*      gcell1  = (int*)  alloc((size_t)N1 * 4);
    int*      qcell1  = (int*)  alloc((size_t)N1 * 4);
    int*      qcell2  = (int*)  alloc((size_t)N2 * 4);
    float4*   gpts0   = (float4*)alloc((size_t)N0 * 16);
    float4*   gpts1   = (float4*)alloc((size_t)N1 * 16);
    int*      qorder1 = (int*)  alloc((size_t)N1 * 4);
    int*      qorder2 = (int*)  alloc((size_t)N2 * 4);
    int*      kidx1   = (int*)  alloc((size_t)N1 * 3 * 4);
    float*    kw1     = (float*)alloc((size_t)N1 * 4 * 4);
    int*      kidx2   = (int*)  alloc((size_t)N2 * 3 * 4);
    float*    kw2     = (float*)alloc((size_t)N2 * 4 * 4);

    auto cdiv = [](int a, int b) { return (a + b - 1) / b; };

    // transforms (one launch)
    k_transform3<<<cdiv(N0 + N1 + N2, 256), 256, 0, stream>>>(pos0, tp0, N0, pos1, tp1, N1,
                                                              pos2, tp2, N2);

    // ---- both kNN levels fused ----
    {
        k_bbox2<<<dim3(BBOXBLK, 2), 256, 0, stream>>>(tp0, N0, tp1, N1, bbp);
        k_gridparams2<<<2, 64, 0, stream>>>(bbp, N0, N1, gps);
        hipMemsetAsync(knncnt, 0, (size_t)4 * MAXC * 4, stream);
        int tot = N0 + 2 * N1 + N2;
        k_cellid4<<<cdiv(tot, 256), 256, 0, stream>>>(tp0, N0, tp1, N1, tp2, N2,
                                                      gcell0, qcell1, gcell1, qcell2,
                                                      knncnt, gps);
        int nbc = cdiv(MAXC, 1024);
        k_scan1c<<<dim3(nbc, 4), 256, 0, stream>>>(knncnt, knnrow, bsum, nbc);
        k_scan2<<<4, 64, 0, stream>>>(bsum, nbc);
        k_scan3c<<<dim3(cdiv(MAXC, 256), 4), 256, 0, stream>>>(knnrow, knncur, bsum, nbc,
                                                               make_int4(N0, N1, N1, N2));
        k_scatter4<<<cdiv(tot, 256), 256, 0, stream>>>(tp0, N0, tp1, N1, tp2, N2,
                                                       gcell0, qcell1, gcell1, qcell2,
                                                       knncur, gpts0, gpts1, qorder1, qorder2);
        k_knn_grid2<<<cdiv(N1 + N2, 256), 256, 0, stream>>>(
            tp1, N1, qorder1, gpts0, knnrow, kidx1, kw1,
            tp2, N2, qorder2, gpts1, knnrow + 2 * (MAXC + 1), kidx2, kw2, gps);
    }

    // ---- all three graph builds batched ----
    {
        hipMemsetAsync(cnt012, 0, (size_t)(N0 + N1 + N2) * 4, stream);
        k_hist3<<<cdiv(E0 + E1 + E2, 256), 256, 0, stream>>>(ei0 + E0, E0, cnt0,
                                                             ei1 + E1, E1, cnt1,
                                                             ei2 + E2, E2, cnt2);
        int nbmax = cdiv(N2, 1024);
        k_scan1t<<<dim3(nbmax, 3), 256, 0, stream>>>(cnt0, rp0, dv0, N0,
                                                     cnt1, rp1, dv1, N1,
                                                     cnt2, rp2, dv2, N2, bsum, nbmax);
        k_scan2<<<3, 64, 0, stream>>>(bsum, nbmax);
        k_scan3t<<<dim3(cdiv(N2, 256), 3), 256, 0, stream>>>(rp0, cur0, E0, N0,
                                                             rp1, cur1, E1, N1,
                                                             rp2, cur2, E2, N2, bsum, nbmax);
        k_scatter3<<<cdiv(E0 + E1 + E2, 256), 256, 0, stream>>>(ei0, E0, cur0, csr0,
                                                                ei1, E1, cur1, csr1,
                                                                ei2, E2, cur2, csr2);
    }

    // x = selu(latent @ W_lin + b_lin)  -> A
    k_matmul128<64, false, true, false, false><<<cdiv(N0, 16), 256, 0, stream>>>(
        latent, nullptr, W_lin, b_lin, nullptr, nullptr, nullptr, A, N0);

    // level 0: two convs (A -> A)
    k_matmul128<128, true, false, true, false><<<cdiv(N0, 16), 256, 0, stream>>>(
        A, pos0, W0, nullptr, dv0, nullptr, nullptr, Bb, N0);
    k_gather128<<<cdiv(N0 * 32, 256), 256, 0, stream>>>(rp0, csr0, (const float4*)Bb, dv0,
                                                        (const float4*)b0, (float4*)A, N0);
    k_matmul128<128, true, false, true, false><<<cdiv(N0, 16), 256, 0, stream>>>(
        A, pos0, W1, nullptr, dv0, nullptr, nullptr, Bb, N0);
    k_gather128<<<cdiv(N0 * 32, 256), 256, 0, stream>>>(rp0, csr0, (const float4*)Bb, dv0,
                                                        (const float4*)b1, (float4*)A, N0);

    // level 1 conv with fused interp from level-0 features in A (kidx1/kw1)
    k_matmul128<128, true, false, true, true><<<cdiv(N1, 16), 256, 0, stream>>>(
        A, pos1, W2, nullptr, dv1, kidx1, kw1, Bb, N1);
    k_gather128<<<cdiv(N1 * 32, 256), 256, 0, stream>>>(rp1, csr1, (const float4*)Bb, dv1,
                                                        (const float4*)b2, (float4*)A, N1);

    // level 2 conv with fused interp from level-1 features in A (kidx2/kw2)
    k_matmul128<128, true, false, true, true><<<cdiv(N2, 16), 256, 0, stream>>>(
        A, pos2, W3, nullptr, dv2, kidx2, kw2, Bb, N2);
    k_gather128<<<cdiv(N2 * 32, 256), 256, 0, stream>>>(rp2, csr2, (const float4*)Bb, dv2,
                                                        (const float4*)b3, (float4*)A, N2);

    // output conv (OC=5)
    k_matmul5<<<cdiv(N2, 32), 256, 0, stream>>>(A, pos2, W4, dv2, xw5, N2);
    k_gather5<<<cdiv(N2 * 8, 256), 256, 0, stream>>>(rp2, csr2, xw5, dv2, b4, out, N2);
}